// Round 1
// baseline (1144.007 us; speedup 1.0000x reference)
//
#include <hip/hip_runtime.h>
#include <math.h>

#define N_NODES 50000
#define N_EDGES 800000
#define NGRAPHS 256
#define NCONV 3

static inline int divup(int a, int b) { return (a + b - 1) / b; }

__global__ void fill_f32(float* p, float v, int n) {
    int i = blockIdx.x * blockDim.x + threadIdx.x;
    if (i < n) p[i] = v;
}
__global__ void fill_i32(int* p, int v, int n) {
    int i = blockIdx.x * blockDim.x + threadIdx.x;
    if (i < n) p[i] = v;
}

// ---------------- CSR build ----------------
__global__ void count_edges(const int* __restrict__ dst, int* __restrict__ deg, int E) {
    int i = blockIdx.x * blockDim.x + threadIdx.x;
    if (i < E) atomicAdd(&deg[dst[i]], 1);
}

__global__ __launch_bounds__(1024) void scan_blocks(const int* __restrict__ deg,
                                                    int* __restrict__ excl,
                                                    int* __restrict__ bsum, int n) {
    __shared__ int buf[1024];
    int tid = threadIdx.x;
    int i = blockIdx.x * 1024 + tid;
    int v = (i < n) ? deg[i] : 0;
    buf[tid] = v;
    __syncthreads();
    for (int off = 1; off < 1024; off <<= 1) {
        int t = (tid >= off) ? buf[tid - off] : 0;
        __syncthreads();
        buf[tid] += t;
        __syncthreads();
    }
    if (i < n) excl[i] = buf[tid] - v;
    if (tid == 1023) bsum[blockIdx.x] = buf[1023];
}

__global__ void scan_sums(int* __restrict__ bsum, int nb) {
    // single thread; nb is small (49)
    int c = 0;
    for (int i = 0; i < nb; i++) { int v = bsum[i]; bsum[i] = c; c += v; }
    bsum[nb] = c;
}

__global__ void scan_add(int* __restrict__ row_ptr, int* __restrict__ cursor,
                         const int* __restrict__ bsum, int n, int nb) {
    int i = blockIdx.x * blockDim.x + threadIdx.x;
    if (i < n) {
        int v = row_ptr[i] + bsum[i >> 10];
        row_ptr[i] = v;
        cursor[i] = v;
    }
    if (i == 0) row_ptr[n] = bsum[nb];
}

__global__ void scatter_edges(const int* __restrict__ src, const int* __restrict__ dst,
                              int* __restrict__ cursor, int* __restrict__ col, int E) {
    int i = blockIdx.x * blockDim.x + threadIdx.x;
    if (i < E) {
        int d = dst[i];
        int p = atomicAdd(&cursor[d], 1);
        col[p] = src[i];
    }
}

__global__ void scatter_loops(int* __restrict__ cursor, int* __restrict__ col, int n) {
    int v = blockIdx.x * blockDim.x + threadIdx.x;
    if (v < n) {
        int p = atomicAdd(&cursor[v], 1);
        col[p] = v;
    }
}

// ---------------- BN stats + fold ----------------
__global__ void colstats(const float* __restrict__ x, int n, float* __restrict__ sums) {
    int c = threadIdx.x;  // 128 threads
    float s = 0.f, s2 = 0.f;
    for (int r = blockIdx.x; r < n; r += gridDim.x) {
        float v = x[r * 128 + c];
        s += v;
        s2 += v * v;
    }
    atomicAdd(&sums[c], s);
    atomicAdd(&sums[128 + c], s2);
}

__global__ void colstats_small(const float* __restrict__ x, int rows, float* __restrict__ sums) {
    int j = threadIdx.x;  // 128
    float s = 0.f, s2 = 0.f;
    for (int r = 0; r < rows; ++r) {
        float v = x[r * 128 + j];
        s += v;
        s2 += v * v;
    }
    sums[j] = s;
    sums[128 + j] = s2;
}

// W' = diag(s)W ; b' = t·W (+extra).  s = g*rsqrt(var+eps), t = b - mean*s
__global__ void fold_kernel(const float* __restrict__ sums, float inv_n,
                            const float* __restrict__ gamma, const float* __restrict__ beta,
                            const float* __restrict__ W, const float* __restrict__ extra,
                            float* __restrict__ Wp, float* __restrict__ bp) {
    __shared__ float sS[128], tS[128];
    int j = threadIdx.x;  // 128
    float mean = sums[j] * inv_n;
    float var = sums[128 + j] * inv_n - mean * mean;
    float sc = gamma[j] * rsqrtf(var + 1e-5f);
    sS[j] = sc;
    tS[j] = beta[j] - mean * sc;
    __syncthreads();
    float acc = extra ? extra[j] : 0.f;
    for (int k = 0; k < 128; ++k) {
        float w = W[k * 128 + j];
        Wp[k * 128 + j] = sS[k] * w;
        acc += tS[k] * w;
    }
    bp[j] = acc;
}

__global__ void fold_cls(const float* __restrict__ sums, float inv_n,
                         const float* __restrict__ gamma, const float* __restrict__ beta,
                         const float* __restrict__ W, const float* __restrict__ b,
                         float* __restrict__ Wp, float* __restrict__ bp) {
    __shared__ float sS[128], tS[128];
    int k = threadIdx.x;  // 128
    float mean = sums[k] * inv_n;
    float var = sums[128 + k] * inv_n - mean * mean;
    float sc = gamma[k] * rsqrtf(var + 1e-5f);
    sS[k] = sc;
    tS[k] = beta[k] - mean * sc;
    __syncthreads();
    for (int i = k; i < 1280; i += 128) {
        int r = i / 10;
        Wp[i] = sS[r] * W[i];
    }
    if (k < 10) {
        float acc = b[k];
        for (int kk = 0; kk < 128; ++kk) acc += tS[kk] * W[kk * 10 + k];
        bp[k] = acc;
    }
}

// ---------------- GEMM: out[n,128] = A[n,128] @ Wp[128,128] + bp, optional relu ----------------
__global__ __launch_bounds__(256) void gemm128(const float* __restrict__ A,
                                               const float* __restrict__ Wp,
                                               const float* __restrict__ bp,
                                               float* __restrict__ out, int n, int relu) {
    __shared__ float Wl[128 * 128];  // 64KB
    __shared__ float hT[128 * 32];   // 16KB, transposed A tile: hT[k][r]
    int tid = threadIdx.x;
    for (int i = tid; i < 4096; i += 256) {
        ((float4*)Wl)[i] = ((const float4*)Wp)[i];
    }
    int base = blockIdx.x * 32;
    for (int pass = 0; pass < 4; ++pass) {
        int r = (tid >> 5) + pass * 8;
        int c4 = tid & 31;
        int row = base + r;
        float4 v = (row < n) ? ((const float4*)(A + (size_t)row * 128))[c4]
                             : make_float4(0.f, 0.f, 0.f, 0.f);
        hT[(c4 * 4 + 0) * 32 + r] = v.x;
        hT[(c4 * 4 + 1) * 32 + r] = v.y;
        hT[(c4 * 4 + 2) * 32 + r] = v.z;
        hT[(c4 * 4 + 3) * 32 + r] = v.w;
    }
    __syncthreads();
    int tx = tid & 31, ty = tid >> 5;
    int j0 = tx * 4, r0 = ty * 4;
    float acc[4][4] = {};
#pragma unroll 8
    for (int k = 0; k < 128; ++k) {
        float4 a = *(const float4*)&hT[k * 32 + r0];
        float4 w = *(const float4*)&Wl[k * 128 + j0];
        acc[0][0] += a.x * w.x; acc[0][1] += a.x * w.y; acc[0][2] += a.x * w.z; acc[0][3] += a.x * w.w;
        acc[1][0] += a.y * w.x; acc[1][1] += a.y * w.y; acc[1][2] += a.y * w.z; acc[1][3] += a.y * w.w;
        acc[2][0] += a.z * w.x; acc[2][1] += a.z * w.y; acc[2][2] += a.z * w.z; acc[2][3] += a.z * w.w;
        acc[3][0] += a.w * w.x; acc[3][1] += a.w * w.y; acc[3][2] += a.w * w.z; acc[3][3] += a.w * w.w;
    }
    float4 bb = *(const float4*)&bp[j0];
    for (int i2 = 0; i2 < 4; ++i2) {
        int row = base + r0 + i2;
        if (row < n) {
            float4 o = make_float4(acc[i2][0] + bb.x, acc[i2][1] + bb.y,
                                   acc[i2][2] + bb.z, acc[i2][3] + bb.w);
            if (relu) {
                o.x = fmaxf(o.x, 0.f); o.y = fmaxf(o.y, 0.f);
                o.z = fmaxf(o.z, 0.f); o.w = fmaxf(o.w, 0.f);
            }
            *(float4*)&out[(size_t)row * 128 + j0] = o;
        }
    }
}

// ---------------- attention logits per node ----------------
__global__ __launch_bounds__(256) void alphas_kernel(const float* __restrict__ hp,
                                                     const float* __restrict__ a_src,
                                                     const float* __restrict__ a_dst,
                                                     float* __restrict__ al_s,
                                                     float* __restrict__ al_d, int n) {
    int lane = threadIdx.x & 63;
    int node = blockIdx.x * 4 + (threadIdx.x >> 6);
    if (node >= n) return;
    int f0 = lane * 2;
    int head = lane >> 4;
    int d0 = f0 & 31;
    float2 v = *(const float2*)&hp[(size_t)node * 128 + f0];
    float2 as = *(const float2*)&a_src[head * 32 + d0];
    float2 ad = *(const float2*)&a_dst[head * 32 + d0];
    float ps = v.x * as.x + v.y * as.y;
    float pd = v.x * ad.x + v.y * ad.y;
    for (int off = 8; off >= 1; off >>= 1) {
        ps += __shfl_xor(ps, off, 64);
        pd += __shfl_xor(pd, off, 64);
    }
    if ((lane & 15) == 0) {
        al_s[node * 4 + head] = ps;
        al_d[node * 4 + head] = pd;
    }
}

__device__ __forceinline__ float leaky(float x) { return fmaxf(x, 0.2f * x); }

// ---------------- GAT aggregation: one wave per dst node ----------------
__global__ __launch_bounds__(256) void gat_aggregate(const float* __restrict__ hp,
                                                     const float* __restrict__ al_s,
                                                     const float* __restrict__ al_d,
                                                     const int* __restrict__ row_ptr,
                                                     const int* __restrict__ col,
                                                     const float* __restrict__ bias,
                                                     float* __restrict__ h_out, int n) {
    int lane = threadIdx.x & 63;
    int node = blockIdx.x * 4 + (threadIdx.x >> 6);
    if (node >= n) return;
    int beg = row_ptr[node], end = row_ptr[node + 1];
    float4 ad = *(const float4*)&al_d[node * 4];
    const float NEG = -1e30f;
    float m0 = NEG, m1 = NEG, m2 = NEG, m3 = NEG;
    for (int e = beg + lane; e < end; e += 64) {
        int s = col[e];
        float4 as = *(const float4*)&al_s[s * 4];
        m0 = fmaxf(m0, leaky(as.x + ad.x));
        m1 = fmaxf(m1, leaky(as.y + ad.y));
        m2 = fmaxf(m2, leaky(as.z + ad.z));
        m3 = fmaxf(m3, leaky(as.w + ad.w));
    }
    for (int off = 32; off >= 1; off >>= 1) {
        m0 = fmaxf(m0, __shfl_xor(m0, off, 64));
        m1 = fmaxf(m1, __shfl_xor(m1, off, 64));
        m2 = fmaxf(m2, __shfl_xor(m2, off, 64));
        m3 = fmaxf(m3, __shfl_xor(m3, off, 64));
    }
    float s0 = 0.f, s1 = 0.f, s2 = 0.f, s3 = 0.f;
    for (int e = beg + lane; e < end; e += 64) {
        int s = col[e];
        float4 as = *(const float4*)&al_s[s * 4];
        s0 += expf(leaky(as.x + ad.x) - m0);
        s1 += expf(leaky(as.y + ad.y) - m1);
        s2 += expf(leaky(as.z + ad.z) - m2);
        s3 += expf(leaky(as.w + ad.w) - m3);
    }
    for (int off = 32; off >= 1; off >>= 1) {
        s0 += __shfl_xor(s0, off, 64);
        s1 += __shfl_xor(s1, off, 64);
        s2 += __shfl_xor(s2, off, 64);
        s3 += __shfl_xor(s3, off, 64);
    }
    float d0 = 1.f / (s0 + 1e-16f), d1 = 1.f / (s1 + 1e-16f);
    float d2 = 1.f / (s2 + 1e-16f), d3 = 1.f / (s3 + 1e-16f);
    int head = lane >> 4;
    float mh = head == 0 ? m0 : head == 1 ? m1 : head == 2 ? m2 : m3;
    float dh = head == 0 ? d0 : head == 1 ? d1 : head == 2 ? d2 : d3;
    float adh = head == 0 ? ad.x : head == 1 ? ad.y : head == 2 ? ad.z : ad.w;
    int f0 = lane * 2;
    float a0 = 0.f, a1 = 0.f;
    for (int e = beg; e < end; ++e) {
        int s = col[e];
        float als = al_s[s * 4 + head];
        float w = expf(leaky(als + adh) - mh) * dh;
        float2 hv = *(const float2*)&hp[(size_t)s * 128 + f0];
        a0 += hv.x * w;
        a1 += hv.y * w;
    }
    float2 bb = *(const float2*)&bias[f0];
    float2 o;
    o.x = fmaxf(a0 + bb.x, 0.f);
    o.y = fmaxf(a1 + bb.y, 0.f);
    *(float2*)&h_out[(size_t)node * 128 + f0] = o;
}

// ---------------- pooling (batch sorted) ----------------
__global__ void pool_kernel(const float* __restrict__ h, const int* __restrict__ batch,
                            float* __restrict__ g, int n, int chunk) {
    int f = threadIdx.x;  // 128
    int a = blockIdx.x * chunk;
    if (a >= n) return;
    int b = min(n, a + chunk);
    float acc = 0.f;
    int cur = batch[a];
    for (int i = a; i < b; ++i) {
        int bi = batch[i];
        if (bi != cur) {
            atomicAdd(&g[cur * 128 + f], acc);
            acc = 0.f;
            cur = bi;
        }
        acc += h[(size_t)i * 128 + f];
    }
    atomicAdd(&g[cur * 128 + f], acc);
}

// ---------------- final classifier + log_softmax ----------------
__global__ void final_kernel(const float* __restrict__ g2, const float* __restrict__ Wpc,
                             const float* __restrict__ bpc, float* __restrict__ out, int rows) {
    int r = blockIdx.x * blockDim.x + threadIdx.x;
    if (r >= rows) return;
    float logit[10];
    for (int j = 0; j < 10; ++j) logit[j] = bpc[j];
    for (int k = 0; k < 128; ++k) {
        float gv = g2[r * 128 + k];
#pragma unroll
        for (int j = 0; j < 10; ++j) logit[j] += gv * Wpc[k * 10 + j];
    }
    float m = logit[0];
    for (int j = 1; j < 10; ++j) m = fmaxf(m, logit[j]);
    float sum = 0.f;
    for (int j = 0; j < 10; ++j) sum += expf(logit[j] - m);
    float lse = m + logf(sum);
    for (int j = 0; j < 10; ++j) out[r * 10 + j] = logit[j] - lse;
}

extern "C" void kernel_launch(void* const* d_in, const int* in_sizes, int n_in,
                              void* d_out, int out_size, void* d_ws, size_t ws_size,
                              hipStream_t stream) {
    const float* x      = (const float*)d_in[0];
    const int*   ei     = (const int*)d_in[1];
    const int*   batch  = (const int*)d_in[2];
    const float* w_feat = (const float*)d_in[3];
    const float* bnf_g  = (const float*)d_in[4];
    const float* bnf_b  = (const float*)d_in[5];
    const float* bnc_g  = (const float*)d_in[6];
    const float* bnc_b  = (const float*)d_in[7];
    const float* gat_w  = (const float*)d_in[8];
    const float* gat_as = (const float*)d_in[9];
    const float* gat_ad = (const float*)d_in[10];
    const float* gat_b  = (const float*)d_in[11];
    const float* bnfc_g = (const float*)d_in[12];
    const float* bnfc_b = (const float*)d_in[13];
    const float* lin_w  = (const float*)d_in[14];
    const float* lin_b  = (const float*)d_in[15];
    const float* bnh_g  = (const float*)d_in[16];
    const float* bnh_b  = (const float*)d_in[17];
    const float* cls_w  = (const float*)d_in[18];
    const float* cls_b  = (const float*)d_in[19];
    float* out = (float*)d_out;

    char* ws = (char*)d_ws;
    size_t off = 0;
    auto alloc = [&](size_t bytes) -> void* {
        void* p = ws + off;
        off = (off + bytes + 255) & ~(size_t)255;
        return p;
    };
    float* h    = (float*)alloc((size_t)N_NODES * 128 * 4);
    float* hp   = (float*)alloc((size_t)N_NODES * 128 * 4);
    float* als  = (float*)alloc((size_t)N_NODES * 4 * 4);
    float* ald  = (float*)alloc((size_t)N_NODES * 4 * 4);
    int*   deg  = (int*)alloc((size_t)N_NODES * 4);
    int*   curs = (int*)alloc((size_t)N_NODES * 4);
    int*   rowp = (int*)alloc((size_t)(N_NODES + 1) * 4);
    int*   col  = (int*)alloc((size_t)(N_EDGES + N_NODES) * 4);
    int*   bsum = (int*)alloc(64 * 4);
    float* sums = (float*)alloc(256 * 4);
    float* Wp   = (float*)alloc(128 * 128 * 4);
    float* bp   = (float*)alloc(128 * 4);
    float* g    = (float*)alloc(NGRAPHS * 128 * 4);
    float* g2   = (float*)alloc(NGRAPHS * 128 * 4);
    float* Wpc  = (float*)alloc(128 * 10 * 4);
    float* bpc  = (float*)alloc(64);

    const int* esrc = ei;
    const int* edst = ei + N_EDGES;
    const int nb = divup(N_NODES, 1024);  // 49

    // ---- CSR build (deg starts at 1: self-loop per node) ----
    fill_i32<<<divup(N_NODES, 256), 256, 0, stream>>>(deg, 1, N_NODES);
    count_edges<<<divup(N_EDGES, 256), 256, 0, stream>>>(edst, deg, N_EDGES);
    scan_blocks<<<nb, 1024, 0, stream>>>(deg, rowp, bsum, N_NODES);
    scan_sums<<<1, 1, 0, stream>>>(bsum, nb);
    scan_add<<<divup(N_NODES, 256), 256, 0, stream>>>(rowp, curs, bsum, N_NODES, nb);
    scatter_edges<<<divup(N_EDGES, 256), 256, 0, stream>>>(esrc, edst, curs, col, N_EDGES);
    scatter_loops<<<divup(N_NODES, 256), 256, 0, stream>>>(curs, col, N_NODES);

    // ---- h = relu(BN(x) @ w_feat) ----
    fill_f32<<<1, 256, 0, stream>>>(sums, 0.f, 256);
    colstats<<<512, 128, 0, stream>>>(x, N_NODES, sums);
    fold_kernel<<<1, 128, 0, stream>>>(sums, 1.f / N_NODES, bnf_g, bnf_b, w_feat, nullptr, Wp, bp);
    gemm128<<<divup(N_NODES, 32), 256, 0, stream>>>(x, Wp, bp, h, N_NODES, 1);

    // ---- 3 GAT conv layers ----
    for (int i = 0; i < NCONV; ++i) {
        fill_f32<<<1, 256, 0, stream>>>(sums, 0.f, 256);
        colstats<<<512, 128, 0, stream>>>(h, N_NODES, sums);
        fold_kernel<<<1, 128, 0, stream>>>(sums, 1.f / N_NODES, bnc_g + 128 * i, bnc_b + 128 * i,
                                           gat_w + 16384 * i, nullptr, Wp, bp);
        gemm128<<<divup(N_NODES, 32), 256, 0, stream>>>(h, Wp, bp, hp, N_NODES, 0);
        alphas_kernel<<<divup(N_NODES, 4), 256, 0, stream>>>(hp, gat_as + 128 * i, gat_ad + 128 * i,
                                                             als, ald, N_NODES);
        gat_aggregate<<<divup(N_NODES, 4), 256, 0, stream>>>(hp, als, ald, rowp, col,
                                                             gat_b + 128 * i, h, N_NODES);
    }

    // ---- pool + MLP head ----
    fill_f32<<<divup(NGRAPHS * 128, 256), 256, 0, stream>>>(g, 0.f, NGRAPHS * 128);
    pool_kernel<<<divup(N_NODES, 256), 128, 0, stream>>>(h, batch, g, N_NODES, 256);
    colstats_small<<<1, 128, 0, stream>>>(g, NGRAPHS, sums);
    fold_kernel<<<1, 128, 0, stream>>>(sums, 1.f / NGRAPHS, bnfc_g, bnfc_b, lin_w, lin_b, Wp, bp);
    gemm128<<<divup(NGRAPHS, 32), 256, 0, stream>>>(g, Wp, bp, g2, NGRAPHS, 1);
    colstats_small<<<1, 128, 0, stream>>>(g2, NGRAPHS, sums);
    fold_cls<<<1, 128, 0, stream>>>(sums, 1.f / NGRAPHS, bnh_g, bnh_b, cls_w, cls_b, Wpc, bpc);
    final_kernel<<<divup(NGRAPHS, 64), 64, 0, stream>>>(g2, Wpc, bpc, out, NGRAPHS);
}

// Round 2
// 1006.137 us; speedup vs baseline: 1.1370x; 1.1370x over previous
//
#include <hip/hip_runtime.h>
#include <math.h>

#define N_NODES 50000
#define N_EDGES 800000
#define NGRAPHS 256
#define NCONV 3

static inline int divup(int a, int b) { return (a + b - 1) / b; }

__global__ void fill_f32(float* p, float v, int n) {
    int i = blockIdx.x * blockDim.x + threadIdx.x;
    if (i < n) p[i] = v;
}
__global__ void fill_i32(int* p, int v, int n) {
    int i = blockIdx.x * blockDim.x + threadIdx.x;
    if (i < n) p[i] = v;
}

// ---------------- CSR build ----------------
__global__ void count_edges(const int* __restrict__ dst, int* __restrict__ deg, int E) {
    int i = blockIdx.x * blockDim.x + threadIdx.x;
    if (i < E) atomicAdd(&deg[dst[i]], 1);
}

__global__ __launch_bounds__(1024) void scan_blocks(const int* __restrict__ deg,
                                                    int* __restrict__ excl,
                                                    int* __restrict__ bsum, int n) {
    __shared__ int buf[1024];
    int tid = threadIdx.x;
    int i = blockIdx.x * 1024 + tid;
    int v = (i < n) ? deg[i] : 0;
    buf[tid] = v;
    __syncthreads();
    for (int off = 1; off < 1024; off <<= 1) {
        int t = (tid >= off) ? buf[tid - off] : 0;
        __syncthreads();
        buf[tid] += t;
        __syncthreads();
    }
    if (i < n) excl[i] = buf[tid] - v;
    if (tid == 1023) bsum[blockIdx.x] = buf[1023];
}

// parallel 64-lane shuffle scan (nb <= 64)
__global__ void scan_sums(int* __restrict__ bsum, int nb) {
    int tid = threadIdx.x;  // 64 threads
    int orig = (tid < nb) ? bsum[tid] : 0;
    int v = orig;
    for (int off = 1; off < 64; off <<= 1) {
        int t = __shfl_up(v, off, 64);
        if (tid >= off) v += t;
    }
    if (tid < nb) bsum[tid] = v - orig;       // exclusive
    if (tid == nb - 1) bsum[nb] = v;          // total
}

__global__ void scan_add(int* __restrict__ row_ptr, int* __restrict__ cursor,
                         const int* __restrict__ bsum, int n, int nb) {
    int i = blockIdx.x * blockDim.x + threadIdx.x;
    if (i < n) {
        int v = row_ptr[i] + bsum[i >> 10];
        row_ptr[i] = v;
        cursor[i] = v;
    }
    if (i == 0) row_ptr[n] = bsum[nb];
}

__global__ void scatter_edges(const int* __restrict__ src, const int* __restrict__ dst,
                              int* __restrict__ cursor, int* __restrict__ col, int E) {
    int i = blockIdx.x * blockDim.x + threadIdx.x;
    if (i < E) {
        int d = dst[i];
        int p = atomicAdd(&cursor[d], 1);
        col[p] = src[i];
    }
}

__global__ void scatter_loops(int* __restrict__ cursor, int* __restrict__ col, int n) {
    int v = blockIdx.x * blockDim.x + threadIdx.x;
    if (v < n) {
        int p = atomicAdd(&cursor[v], 1);
        col[p] = v;
    }
}

// ---------------- BN stats + fold ----------------
__global__ void colstats(const float* __restrict__ x, int n, float* __restrict__ sums) {
    int c = threadIdx.x;  // 128 threads
    float s = 0.f, s2 = 0.f;
    for (int r = blockIdx.x; r < n; r += gridDim.x) {
        float v = x[r * 128 + c];
        s += v;
        s2 += v * v;
    }
    atomicAdd(&sums[c], s);
    atomicAdd(&sums[128 + c], s2);
}

__global__ void colstats_small(const float* __restrict__ x, int rows, float* __restrict__ sums) {
    int j = threadIdx.x;  // 128
    float s = 0.f, s2 = 0.f;
    for (int r = 0; r < rows; ++r) {
        float v = x[r * 128 + j];
        s += v;
        s2 += v * v;
    }
    sums[j] = s;
    sums[128 + j] = s2;
}

// W' = diag(s)W ; b' = t·W (+extra).  s = g*rsqrt(var+eps), t = b - mean*s
__global__ void fold_kernel(const float* __restrict__ sums, float inv_n,
                            const float* __restrict__ gamma, const float* __restrict__ beta,
                            const float* __restrict__ W, const float* __restrict__ extra,
                            float* __restrict__ Wp, float* __restrict__ bp) {
    __shared__ float sS[128], tS[128];
    int j = threadIdx.x;  // 128
    float mean = sums[j] * inv_n;
    float var = sums[128 + j] * inv_n - mean * mean;
    float sc = gamma[j] * rsqrtf(var + 1e-5f);
    sS[j] = sc;
    tS[j] = beta[j] - mean * sc;
    __syncthreads();
    float acc = extra ? extra[j] : 0.f;
#pragma unroll 8
    for (int k = 0; k < 128; ++k) {
        float w = W[k * 128 + j];
        Wp[k * 128 + j] = sS[k] * w;
        acc += tS[k] * w;
    }
    bp[j] = acc;
}

__global__ void fold_cls(const float* __restrict__ sums, float inv_n,
                         const float* __restrict__ gamma, const float* __restrict__ beta,
                         const float* __restrict__ W, const float* __restrict__ b,
                         float* __restrict__ Wp, float* __restrict__ bp) {
    __shared__ float sS[128], tS[128];
    int k = threadIdx.x;  // 128
    float mean = sums[k] * inv_n;
    float var = sums[128 + k] * inv_n - mean * mean;
    float sc = gamma[k] * rsqrtf(var + 1e-5f);
    sS[k] = sc;
    tS[k] = beta[k] - mean * sc;
    __syncthreads();
    for (int i = k; i < 1280; i += 128) {
        int r = i / 10;
        Wp[i] = sS[r] * W[i];
    }
    if (k < 10) {
        float acc = b[k];
        for (int kk = 0; kk < 128; ++kk) acc += tS[kk] * W[kk * 10 + k];
        bp[k] = acc;
    }
}

// ---------------- GEMM: out[n,128] = A[n,128] @ Wp[128,128] + bp ----------------
// optional relu; optional fused attention-logit epilogue (als/ald from pre-relu out)
__global__ __launch_bounds__(256) void gemm128(const float* __restrict__ A,
                                               const float* __restrict__ Wp,
                                               const float* __restrict__ bp,
                                               float* __restrict__ out, int n, int relu,
                                               const float* __restrict__ asrc,
                                               const float* __restrict__ adst,
                                               float* __restrict__ als,
                                               float* __restrict__ ald) {
    __shared__ float Wl[128 * 128];  // 64KB
    __shared__ float hT[128 * 32];   // 16KB, transposed A tile: hT[k][r]
    int tid = threadIdx.x;
    for (int i = tid; i < 4096; i += 256) {
        ((float4*)Wl)[i] = ((const float4*)Wp)[i];
    }
    int base = blockIdx.x * 32;
    for (int pass = 0; pass < 4; ++pass) {
        int r = (tid >> 5) + pass * 8;
        int c4 = tid & 31;
        int row = base + r;
        float4 v = (row < n) ? ((const float4*)(A + (size_t)row * 128))[c4]
                             : make_float4(0.f, 0.f, 0.f, 0.f);
        hT[(c4 * 4 + 0) * 32 + r] = v.x;
        hT[(c4 * 4 + 1) * 32 + r] = v.y;
        hT[(c4 * 4 + 2) * 32 + r] = v.z;
        hT[(c4 * 4 + 3) * 32 + r] = v.w;
    }
    __syncthreads();
    int tx = tid & 31, ty = tid >> 5;
    int j0 = tx * 4, r0 = ty * 4;
    float acc[4][4] = {};
#pragma unroll 8
    for (int k = 0; k < 128; ++k) {
        float4 a = *(const float4*)&hT[k * 32 + r0];
        float4 w = *(const float4*)&Wl[k * 128 + j0];
        acc[0][0] += a.x * w.x; acc[0][1] += a.x * w.y; acc[0][2] += a.x * w.z; acc[0][3] += a.x * w.w;
        acc[1][0] += a.y * w.x; acc[1][1] += a.y * w.y; acc[1][2] += a.y * w.z; acc[1][3] += a.y * w.w;
        acc[2][0] += a.z * w.x; acc[2][1] += a.z * w.y; acc[2][2] += a.z * w.z; acc[2][3] += a.z * w.w;
        acc[3][0] += a.w * w.x; acc[3][1] += a.w * w.y; acc[3][2] += a.w * w.z; acc[3][3] += a.w * w.w;
    }
    float4 bb = *(const float4*)&bp[j0];
    int head = tx >> 3;
    float4 as4 = make_float4(0.f, 0.f, 0.f, 0.f), ad4 = as4;
    if (asrc) {
        as4 = *(const float4*)&asrc[head * 32 + (tx & 7) * 4];
        ad4 = *(const float4*)&adst[head * 32 + (tx & 7) * 4];
    }
    for (int i2 = 0; i2 < 4; ++i2) {
        int row = base + r0 + i2;
        if (row < n) {
            float4 o = make_float4(acc[i2][0] + bb.x, acc[i2][1] + bb.y,
                                   acc[i2][2] + bb.z, acc[i2][3] + bb.w);
            if (asrc) {
                float ps = o.x * as4.x + o.y * as4.y + o.z * as4.z + o.w * as4.w;
                float pd = o.x * ad4.x + o.y * ad4.y + o.z * ad4.z + o.w * ad4.w;
                ps += __shfl_xor(ps, 1, 64); ps += __shfl_xor(ps, 2, 64); ps += __shfl_xor(ps, 4, 64);
                pd += __shfl_xor(pd, 1, 64); pd += __shfl_xor(pd, 2, 64); pd += __shfl_xor(pd, 4, 64);
                if ((tx & 7) == 0) {
                    als[row * 4 + head] = ps;
                    ald[row * 4 + head] = pd;
                }
            }
            if (relu) {
                o.x = fmaxf(o.x, 0.f); o.y = fmaxf(o.y, 0.f);
                o.z = fmaxf(o.z, 0.f); o.w = fmaxf(o.w, 0.f);
            }
            *(float4*)&out[(size_t)row * 128 + j0] = o;
        }
    }
}

__device__ __forceinline__ float leaky(float x) { return fmaxf(x, 0.2f * x); }

// ---------------- GAT aggregation: one wave per dst node ----------------
// pass1: gather al_s once, store logits to wbuf, reduce max
// pass2: read wbuf, expf once per edge-head, store weights, reduce sum
// pass3: 4 edges/iter, 16 lanes x 8 feats, no expf
__global__ __launch_bounds__(256) void gat_aggregate(const float* __restrict__ hp,
                                                     const float* __restrict__ al_s,
                                                     const float* __restrict__ al_d,
                                                     const int* __restrict__ row_ptr,
                                                     const int* __restrict__ col,
                                                     const float* __restrict__ bias,
                                                     float* __restrict__ h_out,
                                                     float* __restrict__ wbuf, int n) {
    int lane = threadIdx.x & 63;
    int node = blockIdx.x * 4 + (threadIdx.x >> 6);
    if (node >= n) return;
    int beg = row_ptr[node], end = row_ptr[node + 1];
    float4 ad = *(const float4*)&al_d[node * 4];
    const float NEG = -1e30f;
    float m0 = NEG, m1 = NEG, m2 = NEG, m3 = NEG;
    for (int e = beg + lane; e < end; e += 64) {
        int s = col[e];
        float4 as = *(const float4*)&al_s[s * 4];
        float4 l;
        l.x = leaky(as.x + ad.x);
        l.y = leaky(as.y + ad.y);
        l.z = leaky(as.z + ad.z);
        l.w = leaky(as.w + ad.w);
        *(float4*)&wbuf[(size_t)e * 4] = l;
        m0 = fmaxf(m0, l.x); m1 = fmaxf(m1, l.y);
        m2 = fmaxf(m2, l.z); m3 = fmaxf(m3, l.w);
    }
    for (int off = 32; off >= 1; off >>= 1) {
        m0 = fmaxf(m0, __shfl_xor(m0, off, 64));
        m1 = fmaxf(m1, __shfl_xor(m1, off, 64));
        m2 = fmaxf(m2, __shfl_xor(m2, off, 64));
        m3 = fmaxf(m3, __shfl_xor(m3, off, 64));
    }
    float s0 = 0.f, s1 = 0.f, s2 = 0.f, s3 = 0.f;
    for (int e = beg + lane; e < end; e += 64) {
        float4 l = *(const float4*)&wbuf[(size_t)e * 4];
        float4 w;
        w.x = expf(l.x - m0); w.y = expf(l.y - m1);
        w.z = expf(l.z - m2); w.w = expf(l.w - m3);
        *(float4*)&wbuf[(size_t)e * 4] = w;
        s0 += w.x; s1 += w.y; s2 += w.z; s3 += w.w;
    }
    for (int off = 32; off >= 1; off >>= 1) {
        s0 += __shfl_xor(s0, off, 64);
        s1 += __shfl_xor(s1, off, 64);
        s2 += __shfl_xor(s2, off, 64);
        s3 += __shfl_xor(s3, off, 64);
    }
    float d0 = 1.f / (s0 + 1e-16f), d1 = 1.f / (s1 + 1e-16f);
    float d2 = 1.f / (s2 + 1e-16f), d3 = 1.f / (s3 + 1e-16f);
    __threadfence_block();  // wbuf weights visible across lanes of this wave
    int q = lane >> 4, l4 = lane & 15;
    int f0 = l4 * 8;
    int head = l4 >> 2;
    float dh = head == 0 ? d0 : head == 1 ? d1 : head == 2 ? d2 : d3;
    float4 a0 = make_float4(0.f, 0.f, 0.f, 0.f), a1 = a0;
    for (int e = beg + q; e < end; e += 4) {
        int s = col[e];
        float w = wbuf[(size_t)e * 4 + head] * dh;
        const float4* rowp4 = (const float4*)&hp[(size_t)s * 128 + f0];
        float4 h0 = rowp4[0], h1 = rowp4[1];
        a0.x += h0.x * w; a0.y += h0.y * w; a0.z += h0.z * w; a0.w += h0.w * w;
        a1.x += h1.x * w; a1.y += h1.y * w; a1.z += h1.z * w; a1.w += h1.w * w;
    }
    for (int off = 16; off <= 32; off <<= 1) {
        a0.x += __shfl_xor(a0.x, off, 64); a0.y += __shfl_xor(a0.y, off, 64);
        a0.z += __shfl_xor(a0.z, off, 64); a0.w += __shfl_xor(a0.w, off, 64);
        a1.x += __shfl_xor(a1.x, off, 64); a1.y += __shfl_xor(a1.y, off, 64);
        a1.z += __shfl_xor(a1.z, off, 64); a1.w += __shfl_xor(a1.w, off, 64);
    }
    if (q == 0) {
        float4 b0 = *(const float4*)&bias[f0];
        float4 b1 = *(const float4*)&bias[f0 + 4];
        float4 o0, o1;
        o0.x = fmaxf(a0.x + b0.x, 0.f); o0.y = fmaxf(a0.y + b0.y, 0.f);
        o0.z = fmaxf(a0.z + b0.z, 0.f); o0.w = fmaxf(a0.w + b0.w, 0.f);
        o1.x = fmaxf(a1.x + b1.x, 0.f); o1.y = fmaxf(a1.y + b1.y, 0.f);
        o1.z = fmaxf(a1.z + b1.z, 0.f); o1.w = fmaxf(a1.w + b1.w, 0.f);
        *(float4*)&h_out[(size_t)node * 128 + f0] = o0;
        *(float4*)&h_out[(size_t)node * 128 + f0 + 4] = o1;
    }
}

// ---------------- pooling (batch sorted) ----------------
__global__ void pool_kernel(const float* __restrict__ h, const int* __restrict__ batch,
                            float* __restrict__ g, int n, int chunk) {
    int f = threadIdx.x;  // 128
    int a = blockIdx.x * chunk;
    if (a >= n) return;
    int b = min(n, a + chunk);
    float acc = 0.f;
    int cur = batch[a];
    for (int i = a; i < b; ++i) {
        int bi = batch[i];
        if (bi != cur) {
            atomicAdd(&g[cur * 128 + f], acc);
            acc = 0.f;
            cur = bi;
        }
        acc += h[(size_t)i * 128 + f];
    }
    atomicAdd(&g[cur * 128 + f], acc);
}

// ---------------- final classifier + log_softmax ----------------
__global__ void final_kernel(const float* __restrict__ g2, const float* __restrict__ Wpc,
                             const float* __restrict__ bpc, float* __restrict__ out, int rows) {
    int r = blockIdx.x * blockDim.x + threadIdx.x;
    if (r >= rows) return;
    float logit[10];
    for (int j = 0; j < 10; ++j) logit[j] = bpc[j];
    for (int k = 0; k < 128; ++k) {
        float gv = g2[r * 128 + k];
#pragma unroll
        for (int j = 0; j < 10; ++j) logit[j] += gv * Wpc[k * 10 + j];
    }
    float m = logit[0];
    for (int j = 1; j < 10; ++j) m = fmaxf(m, logit[j]);
    float sum = 0.f;
    for (int j = 0; j < 10; ++j) sum += expf(logit[j] - m);
    float lse = m + logf(sum);
    for (int j = 0; j < 10; ++j) out[r * 10 + j] = logit[j] - lse;
}

extern "C" void kernel_launch(void* const* d_in, const int* in_sizes, int n_in,
                              void* d_out, int out_size, void* d_ws, size_t ws_size,
                              hipStream_t stream) {
    const float* x      = (const float*)d_in[0];
    const int*   ei     = (const int*)d_in[1];
    const int*   batch  = (const int*)d_in[2];
    const float* w_feat = (const float*)d_in[3];
    const float* bnf_g  = (const float*)d_in[4];
    const float* bnf_b  = (const float*)d_in[5];
    const float* bnc_g  = (const float*)d_in[6];
    const float* bnc_b  = (const float*)d_in[7];
    const float* gat_w  = (const float*)d_in[8];
    const float* gat_as = (const float*)d_in[9];
    const float* gat_ad = (const float*)d_in[10];
    const float* gat_b  = (const float*)d_in[11];
    const float* bnfc_g = (const float*)d_in[12];
    const float* bnfc_b = (const float*)d_in[13];
    const float* lin_w  = (const float*)d_in[14];
    const float* lin_b  = (const float*)d_in[15];
    const float* bnh_g  = (const float*)d_in[16];
    const float* bnh_b  = (const float*)d_in[17];
    const float* cls_w  = (const float*)d_in[18];
    const float* cls_b  = (const float*)d_in[19];
    float* out = (float*)d_out;

    char* ws = (char*)d_ws;
    size_t off = 0;
    auto alloc = [&](size_t bytes) -> void* {
        void* p = ws + off;
        off = (off + bytes + 255) & ~(size_t)255;
        return p;
    };
    float* h    = (float*)alloc((size_t)N_NODES * 128 * 4);
    float* hp   = (float*)alloc((size_t)N_NODES * 128 * 4);
    float* als  = (float*)alloc((size_t)N_NODES * 4 * 4);
    float* ald  = (float*)alloc((size_t)N_NODES * 4 * 4);
    int*   deg  = (int*)alloc((size_t)N_NODES * 4);
    int*   curs = (int*)alloc((size_t)N_NODES * 4);
    int*   rowp = (int*)alloc((size_t)(N_NODES + 1) * 4);
    int*   col  = (int*)alloc((size_t)(N_EDGES + N_NODES) * 4);
    float* wbuf = (float*)alloc((size_t)(N_EDGES + N_NODES) * 4 * 4);
    int*   bsum = (int*)alloc(64 * 4);
    float* sums = (float*)alloc(256 * 4);
    float* Wp   = (float*)alloc(128 * 128 * 4);
    float* bp   = (float*)alloc(128 * 4);
    float* g    = (float*)alloc(NGRAPHS * 128 * 4);
    float* g2   = (float*)alloc(NGRAPHS * 128 * 4);
    float* Wpc  = (float*)alloc(128 * 10 * 4);
    float* bpc  = (float*)alloc(64);

    const int* esrc = ei;
    const int* edst = ei + N_EDGES;
    const int nb = divup(N_NODES, 1024);  // 49

    // ---- CSR build (deg starts at 1: self-loop per node) ----
    fill_i32<<<divup(N_NODES, 256), 256, 0, stream>>>(deg, 1, N_NODES);
    count_edges<<<divup(N_EDGES, 256), 256, 0, stream>>>(edst, deg, N_EDGES);
    scan_blocks<<<nb, 1024, 0, stream>>>(deg, rowp, bsum, N_NODES);
    scan_sums<<<1, 64, 0, stream>>>(bsum, nb);
    scan_add<<<divup(N_NODES, 256), 256, 0, stream>>>(rowp, curs, bsum, N_NODES, nb);
    scatter_edges<<<divup(N_EDGES, 256), 256, 0, stream>>>(esrc, edst, curs, col, N_EDGES);
    scatter_loops<<<divup(N_NODES, 256), 256, 0, stream>>>(curs, col, N_NODES);

    // ---- h = relu(BN(x) @ w_feat) ----
    fill_f32<<<1, 256, 0, stream>>>(sums, 0.f, 256);
    colstats<<<512, 128, 0, stream>>>(x, N_NODES, sums);
    fold_kernel<<<1, 128, 0, stream>>>(sums, 1.f / N_NODES, bnf_g, bnf_b, w_feat, nullptr, Wp, bp);
    gemm128<<<divup(N_NODES, 32), 256, 0, stream>>>(x, Wp, bp, h, N_NODES, 1,
                                                    nullptr, nullptr, nullptr, nullptr);

    // ---- 3 GAT conv layers ----
    for (int i = 0; i < NCONV; ++i) {
        fill_f32<<<1, 256, 0, stream>>>(sums, 0.f, 256);
        colstats<<<512, 128, 0, stream>>>(h, N_NODES, sums);
        fold_kernel<<<1, 128, 0, stream>>>(sums, 1.f / N_NODES, bnc_g + 128 * i, bnc_b + 128 * i,
                                           gat_w + 16384 * i, nullptr, Wp, bp);
        gemm128<<<divup(N_NODES, 32), 256, 0, stream>>>(h, Wp, bp, hp, N_NODES, 0,
                                                        gat_as + 128 * i, gat_ad + 128 * i, als, ald);
        gat_aggregate<<<divup(N_NODES, 4), 256, 0, stream>>>(hp, als, ald, rowp, col,
                                                             gat_b + 128 * i, h, wbuf, N_NODES);
    }

    // ---- pool + MLP head ----
    fill_f32<<<divup(NGRAPHS * 128, 256), 256, 0, stream>>>(g, 0.f, NGRAPHS * 128);
    pool_kernel<<<divup(N_NODES, 256), 128, 0, stream>>>(h, batch, g, N_NODES, 256);
    colstats_small<<<1, 128, 0, stream>>>(g, NGRAPHS, sums);
    fold_kernel<<<1, 128, 0, stream>>>(sums, 1.f / NGRAPHS, bnfc_g, bnfc_b, lin_w, lin_b, Wp, bp);
    gemm128<<<divup(NGRAPHS, 32), 256, 0, stream>>>(g, Wp, bp, g2, NGRAPHS, 1,
                                                    nullptr, nullptr, nullptr, nullptr);
    colstats_small<<<1, 128, 0, stream>>>(g2, NGRAPHS, sums);
    fold_cls<<<1, 128, 0, stream>>>(sums, 1.f / NGRAPHS, bnh_g, bnh_b, cls_w, cls_b, Wpc, bpc);
    final_kernel<<<divup(NGRAPHS, 64), 64, 0, stream>>>(g2, Wpc, bpc, out, NGRAPHS);
}

// Round 3
// 802.716 us; speedup vs baseline: 1.4252x; 1.2534x over previous
//
#include <hip/hip_runtime.h>
#include <math.h>

#define N_NODES 50000
#define N_EDGES 800000
#define NGRAPHS 256
#define NCONV 3

typedef _Float16 h4 __attribute__((ext_vector_type(4)));
typedef _Float16 h8 __attribute__((ext_vector_type(8)));
typedef float f32x4 __attribute__((ext_vector_type(4)));

static inline int divup(int a, int b) { return (a + b - 1) / b; }

__global__ void fill_i32(int* p, int v, int n) {
    int i = blockIdx.x * blockDim.x + threadIdx.x;
    if (i < n) p[i] = v;
}

__global__ void cast_f32_f16(const float* __restrict__ x, _Float16* __restrict__ y, int n4) {
    int i = blockIdx.x * blockDim.x + threadIdx.x;
    if (i < n4) {
        float4 v = ((const float4*)x)[i];
        h4 o;
        o[0] = (_Float16)v.x; o[1] = (_Float16)v.y;
        o[2] = (_Float16)v.z; o[3] = (_Float16)v.w;
        *(h4*)&y[i * 4] = o;
    }
}

// ---------------- CSR build ----------------
__global__ void count_edges(const int* __restrict__ dst, int* __restrict__ deg, int E) {
    int i = blockIdx.x * blockDim.x + threadIdx.x;
    if (i < E) atomicAdd(&deg[dst[i]], 1);
}

__global__ __launch_bounds__(1024) void scan_blocks(const int* __restrict__ deg,
                                                    int* __restrict__ excl,
                                                    int* __restrict__ bsum, int n) {
    __shared__ int buf[1024];
    int tid = threadIdx.x;
    int i = blockIdx.x * 1024 + tid;
    int v = (i < n) ? deg[i] : 0;
    buf[tid] = v;
    __syncthreads();
    for (int off = 1; off < 1024; off <<= 1) {
        int t = (tid >= off) ? buf[tid - off] : 0;
        __syncthreads();
        buf[tid] += t;
        __syncthreads();
    }
    if (i < n) excl[i] = buf[tid] - v;
    if (tid == 1023) bsum[blockIdx.x] = buf[1023];
}

__global__ void scan_sums(int* __restrict__ bsum, int nb) {
    int tid = threadIdx.x;  // 64
    int orig = (tid < nb) ? bsum[tid] : 0;
    int v = orig;
    for (int off = 1; off < 64; off <<= 1) {
        int t = __shfl_up(v, off, 64);
        if (tid >= off) v += t;
    }
    if (tid < nb) bsum[tid] = v - orig;
    if (tid == nb - 1) bsum[nb] = v;
}

__global__ void scan_add(int* __restrict__ row_ptr, int* __restrict__ cursor,
                         const int* __restrict__ bsum, int n, int nb) {
    int i = blockIdx.x * blockDim.x + threadIdx.x;
    if (i < n) {
        int v = row_ptr[i] + bsum[i >> 10];
        row_ptr[i] = v;
        cursor[i] = v;
    }
    if (i == 0) row_ptr[n] = bsum[nb];
}

__global__ void scatter_edges(const int* __restrict__ src, const int* __restrict__ dst,
                              int* __restrict__ cursor, int* __restrict__ col, int E) {
    int i = blockIdx.x * blockDim.x + threadIdx.x;
    if (i < E) {
        int d = dst[i];
        int p = atomicAdd(&cursor[d], 1);
        col[p] = src[i];
    }
}

// also zeroes sums (runs before first colstats)
__global__ void scatter_loops(int* __restrict__ cursor, int* __restrict__ col,
                              float* __restrict__ sums, int n) {
    if (blockIdx.x == 0 && threadIdx.x < 256) sums[threadIdx.x] = 0.f;
    int v = blockIdx.x * blockDim.x + threadIdx.x;
    if (v < n) {
        int p = atomicAdd(&cursor[v], 1);
        col[p] = v;
    }
}

// ---------------- BN stats ----------------
__global__ void colstats(const float* __restrict__ x, int n, float* __restrict__ sums) {
    int c = threadIdx.x;  // 128
    float s = 0.f, s2 = 0.f;
    for (int r = blockIdx.x; r < n; r += gridDim.x) {
        float v = x[r * 128 + c];
        s += v;
        s2 += v * v;
    }
    atomicAdd(&sums[c], s);
    atomicAdd(&sums[128 + c], s2);
}

__global__ void colstats_h(const _Float16* __restrict__ x, int n, float* __restrict__ sums) {
    int c = threadIdx.x;  // 128
    float s = 0.f, s2 = 0.f;
    for (int r = blockIdx.x; r < n; r += gridDim.x) {
        float v = (float)x[r * 128 + c];
        s += v;
        s2 += v * v;
    }
    atomicAdd(&sums[c], s);
    atomicAdd(&sums[128 + c], s2);
}

__global__ void colstats_small(const float* __restrict__ x, int rows, float* __restrict__ sums) {
    int j = threadIdx.x;  // 128
    float s = 0.f, s2 = 0.f;
    for (int r = 0; r < rows; ++r) {
        float v = x[r * 128 + j];
        s += v;
        s2 += v * v;
    }
    sums[j] = s;
    sums[128 + j] = s2;
}

// ---------------- BN folds ----------------
// fp16 transposed fold for MFMA GEMMs: WTh[j][k] = half(s[k]*W[k][j]); bp[j] = sum_k t[k]W[k][j]
__global__ void fold_t(const float* __restrict__ sums, float inv_n,
                       const float* __restrict__ gamma, const float* __restrict__ beta,
                       const float* __restrict__ W,
                       _Float16* __restrict__ WTh, float* __restrict__ bp) {
    __shared__ float sS[128], tS[128];
    int j = threadIdx.x;  // 128
    float mean = sums[j] * inv_n;
    float var = sums[128 + j] * inv_n - mean * mean;
    float sc = gamma[j] * rsqrtf(var + 1e-5f);
    sS[j] = sc;
    tS[j] = beta[j] - mean * sc;
    __syncthreads();
    float acc = 0.f;
#pragma unroll 8
    for (int k = 0; k < 128; ++k) {
        float w = W[k * 128 + j];
        WTh[j * 128 + k] = (_Float16)(sS[k] * w);
        acc += tS[k] * w;
    }
    bp[j] = acc;
}

// f32 fold (head path)
__global__ void fold_kernel(const float* __restrict__ sums, float inv_n,
                            const float* __restrict__ gamma, const float* __restrict__ beta,
                            const float* __restrict__ W, const float* __restrict__ extra,
                            float* __restrict__ Wp, float* __restrict__ bp) {
    __shared__ float sS[128], tS[128];
    int j = threadIdx.x;
    float mean = sums[j] * inv_n;
    float var = sums[128 + j] * inv_n - mean * mean;
    float sc = gamma[j] * rsqrtf(var + 1e-5f);
    sS[j] = sc;
    tS[j] = beta[j] - mean * sc;
    __syncthreads();
    float acc = extra ? extra[j] : 0.f;
#pragma unroll 8
    for (int k = 0; k < 128; ++k) {
        float w = W[k * 128 + j];
        Wp[k * 128 + j] = sS[k] * w;
        acc += tS[k] * w;
    }
    bp[j] = acc;
}

__global__ void fold_cls(const float* __restrict__ sums, float inv_n,
                         const float* __restrict__ gamma, const float* __restrict__ beta,
                         const float* __restrict__ W, const float* __restrict__ b,
                         float* __restrict__ Wp, float* __restrict__ bp) {
    __shared__ float sS[128], tS[128];
    int k = threadIdx.x;
    float mean = sums[k] * inv_n;
    float var = sums[128 + k] * inv_n - mean * mean;
    float sc = gamma[k] * rsqrtf(var + 1e-5f);
    sS[k] = sc;
    tS[k] = beta[k] - mean * sc;
    __syncthreads();
    for (int i = k; i < 1280; i += 128) {
        int r = i / 10;
        Wp[i] = sS[r] * W[i];
    }
    if (k < 10) {
        float acc = b[k];
        for (int kk = 0; kk < 128; ++kk) acc += tS[kk] * W[kk * 10 + k];
        bp[k] = acc;
    }
}

// ---------------- MFMA fp16 GEMM: out[n,128] = A[n,128] @ W'[128,128] + bp ----------------
// WTh is W' transposed ([j][k]). Optional relu; optional fused alpha-logit epilogue.
// Also zeroes sums[0..255] (for the next layer's colstats).
__global__ __launch_bounds__(256) void gemm_mfma(const _Float16* __restrict__ Ah,
                                                 const _Float16* __restrict__ WTh,
                                                 const float* __restrict__ bp,
                                                 _Float16* __restrict__ outh, int n, int relu,
                                                 const float* __restrict__ asrc,
                                                 const float* __restrict__ adst,
                                                 float* __restrict__ als,
                                                 float* __restrict__ ald,
                                                 float* __restrict__ sums_zero) {
    __shared__ _Float16 Wl[128 * 136];  // +8 halves pad per row: conflict-free b128
    int tid = threadIdx.x;
    if (blockIdx.x == 0 && tid < 256 && sums_zero) sums_zero[tid] = 0.f;
    for (int i = tid; i < 2048; i += 256) {
        int r = i >> 4, s = i & 15;
        *(h8*)&Wl[r * 136 + s * 8] = *(const h8*)&WTh[r * 128 + s * 8];
    }
    __syncthreads();
    int lane = tid & 63, wid = tid >> 6;
    int m = lane & 15, quad = lane >> 4;
    int rbase = blockIdx.x * 64 + wid * 16;
    if (rbase >= n) return;  // n % 16 == 0 for all call sites

    const _Float16* arow = Ah + (size_t)(rbase + m) * 128 + quad * 8;
    h8 af0 = *(const h8*)(arow);
    h8 af1 = *(const h8*)(arow + 32);
    h8 af2 = *(const h8*)(arow + 64);
    h8 af3 = *(const h8*)(arow + 96);

    float ps[4][4] = {}, pd[4][4] = {};
    const bool do_al = (asrc != nullptr);

#pragma unroll
    for (int t = 0; t < 8; ++t) {
        const _Float16* wrow = &Wl[(t * 16 + m) * 136 + quad * 8];
        f32x4 acc = {0.f, 0.f, 0.f, 0.f};
        acc = __builtin_amdgcn_mfma_f32_16x16x32_f16(af0, *(const h8*)(wrow), acc, 0, 0, 0);
        acc = __builtin_amdgcn_mfma_f32_16x16x32_f16(af1, *(const h8*)(wrow + 32), acc, 0, 0, 0);
        acc = __builtin_amdgcn_mfma_f32_16x16x32_f16(af2, *(const h8*)(wrow + 64), acc, 0, 0, 0);
        acc = __builtin_amdgcn_mfma_f32_16x16x32_f16(af3, *(const h8*)(wrow + 96), acc, 0, 0, 0);
        int j = t * 16 + m;
        float bj = bp[j];
        float avs = 0.f, avd = 0.f;
        if (do_al) { avs = asrc[j]; avd = adst[j]; }
        int hh = t >> 1;
#pragma unroll
        for (int r = 0; r < 4; ++r) {
            float o = acc[r] + bj;
            if (do_al) {
                ps[r][hh] += o * avs;
                pd[r][hh] += o * avd;
            }
            float v = relu ? fmaxf(o, 0.f) : o;
            int row = rbase + quad * 4 + r;
            outh[(size_t)row * 128 + j] = (_Float16)v;
        }
    }
    if (do_al) {
#pragma unroll
        for (int r = 0; r < 4; ++r) {
#pragma unroll
            for (int hh = 0; hh < 4; ++hh) {
                float v = ps[r][hh];
                v += __shfl_xor(v, 1, 64); v += __shfl_xor(v, 2, 64);
                v += __shfl_xor(v, 4, 64); v += __shfl_xor(v, 8, 64);
                float w = pd[r][hh];
                w += __shfl_xor(w, 1, 64); w += __shfl_xor(w, 2, 64);
                w += __shfl_xor(w, 4, 64); w += __shfl_xor(w, 8, 64);
                if (m == 0) {
                    int row = rbase + quad * 4 + r;
                    als[row * 4 + hh] = v;
                    ald[row * 4 + hh] = w;
                }
            }
        }
    }
}

__device__ __forceinline__ float leaky(float x) { return fmaxf(x, 0.2f * x); }

// ---------------- GAT aggregation: one wave per dst node, 2 passes ----------------
// pass A: gather al_s once, shifted logits -> wbuf (fp16), accumulate exp-sums
// pass B: 4 edges/iter x 16 feature-lanes, recompute exp from wbuf, gather fp16 hp rows
// Also zeroes g[NGRAPHS*128] (blocks 0..127) for the later pool.
__global__ __launch_bounds__(256) void gat_aggregate(const _Float16* __restrict__ hp,
                                                     const float* __restrict__ al_s,
                                                     const float* __restrict__ al_d,
                                                     const int* __restrict__ row_ptr,
                                                     const int* __restrict__ col,
                                                     const float* __restrict__ bias,
                                                     _Float16* __restrict__ h_out,
                                                     _Float16* __restrict__ wbuf,
                                                     float* __restrict__ g_zero, int n) {
    if (blockIdx.x < 128) g_zero[blockIdx.x * 256 + threadIdx.x] = 0.f;
    int lane = threadIdx.x & 63;
    int node = blockIdx.x * 4 + (threadIdx.x >> 6);
    if (node >= n) return;
    int beg = row_ptr[node], end = row_ptr[node + 1];
    float4 ad = *(const float4*)&al_d[node * 4];
    // per-node shift (softmax is shift-invariant; keeps exponents ~O(1))
    float4 c;
    c.x = leaky(ad.x); c.y = leaky(ad.y); c.z = leaky(ad.z); c.w = leaky(ad.w);
    float s0 = 0.f, s1 = 0.f, s2 = 0.f, s3 = 0.f;
    for (int e = beg + lane; e < end; e += 64) {
        int s = col[e];
        float4 as = *(const float4*)&al_s[s * 4];
        float l0 = fminf(leaky(as.x + ad.x) - c.x, 30.f);
        float l1 = fminf(leaky(as.y + ad.y) - c.y, 30.f);
        float l2 = fminf(leaky(as.z + ad.z) - c.z, 30.f);
        float l3 = fminf(leaky(as.w + ad.w) - c.w, 30.f);
        h4 lh;
        lh[0] = (_Float16)l0; lh[1] = (_Float16)l1;
        lh[2] = (_Float16)l2; lh[3] = (_Float16)l3;
        *(h4*)&wbuf[(size_t)e * 4] = lh;
        s0 += expf((float)lh[0]); s1 += expf((float)lh[1]);
        s2 += expf((float)lh[2]); s3 += expf((float)lh[3]);
    }
    for (int off = 32; off >= 1; off >>= 1) {
        s0 += __shfl_xor(s0, off, 64);
        s1 += __shfl_xor(s1, off, 64);
        s2 += __shfl_xor(s2, off, 64);
        s3 += __shfl_xor(s3, off, 64);
    }
    float d0 = 1.f / (s0 + 1e-16f), d1 = 1.f / (s1 + 1e-16f);
    float d2 = 1.f / (s2 + 1e-16f), d3 = 1.f / (s3 + 1e-16f);
    __threadfence_block();  // wbuf visible across lanes of this wave
    int q = lane >> 4, l4 = lane & 15;
    int f0 = l4 * 8;
    int head = l4 >> 2;
    float dh = head == 0 ? d0 : head == 1 ? d1 : head == 2 ? d2 : d3;
    float a0 = 0.f, a1 = 0.f, a2 = 0.f, a3 = 0.f, a4 = 0.f, a5 = 0.f, a6 = 0.f, a7 = 0.f;
    for (int e = beg + q; e < end; e += 4) {
        int s = col[e];
        float w = expf((float)wbuf[(size_t)e * 4 + head]) * dh;
        h8 hv = *(const h8*)&hp[(size_t)s * 128 + f0];
        a0 += (float)hv[0] * w; a1 += (float)hv[1] * w;
        a2 += (float)hv[2] * w; a3 += (float)hv[3] * w;
        a4 += (float)hv[4] * w; a5 += (float)hv[5] * w;
        a6 += (float)hv[6] * w; a7 += (float)hv[7] * w;
    }
#pragma unroll
    for (int off = 16; off <= 32; off <<= 1) {
        a0 += __shfl_xor(a0, off, 64); a1 += __shfl_xor(a1, off, 64);
        a2 += __shfl_xor(a2, off, 64); a3 += __shfl_xor(a3, off, 64);
        a4 += __shfl_xor(a4, off, 64); a5 += __shfl_xor(a5, off, 64);
        a6 += __shfl_xor(a6, off, 64); a7 += __shfl_xor(a7, off, 64);
    }
    if (q == 0) {
        float4 b0 = *(const float4*)&bias[f0];
        float4 b1 = *(const float4*)&bias[f0 + 4];
        h8 ov;
        ov[0] = (_Float16)fmaxf(a0 + b0.x, 0.f);
        ov[1] = (_Float16)fmaxf(a1 + b0.y, 0.f);
        ov[2] = (_Float16)fmaxf(a2 + b0.z, 0.f);
        ov[3] = (_Float16)fmaxf(a3 + b0.w, 0.f);
        ov[4] = (_Float16)fmaxf(a4 + b1.x, 0.f);
        ov[5] = (_Float16)fmaxf(a5 + b1.y, 0.f);
        ov[6] = (_Float16)fmaxf(a6 + b1.z, 0.f);
        ov[7] = (_Float16)fmaxf(a7 + b1.w, 0.f);
        *(h8*)&h_out[(size_t)node * 128 + f0] = ov;
    }
}

// ---------------- pooling (batch sorted) ----------------
__global__ void pool_kernel(const _Float16* __restrict__ h, const int* __restrict__ batch,
                            float* __restrict__ g, int n, int chunk) {
    int f = threadIdx.x;  // 128
    int a = blockIdx.x * chunk;
    if (a >= n) return;
    int b = min(n, a + chunk);
    float acc = 0.f;
    int cur = batch[a];
    for (int i = a; i < b; ++i) {
        int bi = batch[i];
        if (bi != cur) {
            atomicAdd(&g[cur * 128 + f], acc);
            acc = 0.f;
            cur = bi;
        }
        acc += (float)h[(size_t)i * 128 + f];
    }
    atomicAdd(&g[cur * 128 + f], acc);
}

// ---------------- head GEMM (f32, n=256) ----------------
__global__ __launch_bounds__(256) void gemm128(const float* __restrict__ A,
                                               const float* __restrict__ Wp,
                                               const float* __restrict__ bp,
                                               float* __restrict__ out, int n, int relu) {
    __shared__ float Wl[128 * 128];
    __shared__ float hT[128 * 32];
    int tid = threadIdx.x;
    for (int i = tid; i < 4096; i += 256) {
        ((float4*)Wl)[i] = ((const float4*)Wp)[i];
    }
    int base = blockIdx.x * 32;
    for (int pass = 0; pass < 4; ++pass) {
        int r = (tid >> 5) + pass * 8;
        int c4 = tid & 31;
        int row = base + r;
        float4 v = (row < n) ? ((const float4*)(A + (size_t)row * 128))[c4]
                             : make_float4(0.f, 0.f, 0.f, 0.f);
        hT[(c4 * 4 + 0) * 32 + r] = v.x;
        hT[(c4 * 4 + 1) * 32 + r] = v.y;
        hT[(c4 * 4 + 2) * 32 + r] = v.z;
        hT[(c4 * 4 + 3) * 32 + r] = v.w;
    }
    __syncthreads();
    int tx = tid & 31, ty = tid >> 5;
    int j0 = tx * 4, r0 = ty * 4;
    float acc[4][4] = {};
#pragma unroll 8
    for (int k = 0; k < 128; ++k) {
        float4 a = *(const float4*)&hT[k * 32 + r0];
        float4 w = *(const float4*)&Wl[k * 128 + j0];
        acc[0][0] += a.x * w.x; acc[0][1] += a.x * w.y; acc[0][2] += a.x * w.z; acc[0][3] += a.x * w.w;
        acc[1][0] += a.y * w.x; acc[1][1] += a.y * w.y; acc[1][2] += a.y * w.z; acc[1][3] += a.y * w.w;
        acc[2][0] += a.z * w.x; acc[2][1] += a.z * w.y; acc[2][2] += a.z * w.z; acc[2][3] += a.z * w.w;
        acc[3][0] += a.w * w.x; acc[3][1] += a.w * w.y; acc[3][2] += a.w * w.z; acc[3][3] += a.w * w.w;
    }
    float4 bb = *(const float4*)&bp[j0];
    for (int i2 = 0; i2 < 4; ++i2) {
        int row = base + r0 + i2;
        if (row < n) {
            float4 o = make_float4(acc[i2][0] + bb.x, acc[i2][1] + bb.y,
                                   acc[i2][2] + bb.z, acc[i2][3] + bb.w);
            if (relu) {
                o.x = fmaxf(o.x, 0.f); o.y = fmaxf(o.y, 0.f);
                o.z = fmaxf(o.z, 0.f); o.w = fmaxf(o.w, 0.f);
            }
            *(float4*)&out[(size_t)row * 128 + j0] = o;
        }
    }
}

// ---------------- final classifier + log_softmax ----------------
__global__ void final_kernel(const float* __restrict__ g2, const float* __restrict__ Wpc,
                             const float* __restrict__ bpc, float* __restrict__ out, int rows) {
    int r = blockIdx.x * blockDim.x + threadIdx.x;
    if (r >= rows) return;
    float logit[10];
    for (int j = 0; j < 10; ++j) logit[j] = bpc[j];
    for (int k = 0; k < 128; ++k) {
        float gv = g2[r * 128 + k];
#pragma unroll
        for (int j = 0; j < 10; ++j) logit[j] += gv * Wpc[k * 10 + j];
    }
    float m = logit[0];
    for (int j = 1; j < 10; ++j) m = fmaxf(m, logit[j]);
    float sum = 0.f;
    for (int j = 0; j < 10; ++j) sum += expf(logit[j] - m);
    float lse = m + logf(sum);
    for (int j = 0; j < 10; ++j) out[r * 10 + j] = logit[j] - lse;
}

extern "C" void kernel_launch(void* const* d_in, const int* in_sizes, int n_in,
                              void* d_out, int out_size, void* d_ws, size_t ws_size,
                              hipStream_t stream) {
    const float* x      = (const float*)d_in[0];
    const int*   ei     = (const int*)d_in[1];
    const int*   batch  = (const int*)d_in[2];
    const float* w_feat = (const float*)d_in[3];
    const float* bnf_g  = (const float*)d_in[4];
    const float* bnf_b  = (const float*)d_in[5];
    const float* bnc_g  = (const float*)d_in[6];
    const float* bnc_b  = (const float*)d_in[7];
    const float* gat_w  = (const float*)d_in[8];
    const float* gat_as = (const float*)d_in[9];
    const float* gat_ad = (const float*)d_in[10];
    const float* gat_b  = (const float*)d_in[11];
    const float* bnfc_g = (const float*)d_in[12];
    const float* bnfc_b = (const float*)d_in[13];
    const float* lin_w  = (const float*)d_in[14];
    const float* lin_b  = (const float*)d_in[15];
    const float* bnh_g  = (const float*)d_in[16];
    const float* bnh_b  = (const float*)d_in[17];
    const float* cls_w  = (const float*)d_in[18];
    const float* cls_b  = (const float*)d_in[19];
    float* out = (float*)d_out;

    char* ws = (char*)d_ws;
    size_t off = 0;
    auto alloc = [&](size_t bytes) -> void* {
        void* p = ws + off;
        off = (off + bytes + 255) & ~(size_t)255;
        return p;
    };
    _Float16* xh   = (_Float16*)alloc((size_t)N_NODES * 128 * 2);
    _Float16* h    = (_Float16*)alloc((size_t)N_NODES * 128 * 2);
    _Float16* hp   = (_Float16*)alloc((size_t)N_NODES * 128 * 2);
    float*    als  = (float*)alloc((size_t)N_NODES * 4 * 4);
    float*    ald  = (float*)alloc((size_t)N_NODES * 4 * 4);
    int*      deg  = (int*)alloc((size_t)N_NODES * 4);
    int*      curs = (int*)alloc((size_t)N_NODES * 4);
    int*      rowp = (int*)alloc((size_t)(N_NODES + 1) * 4);
    int*      col  = (int*)alloc((size_t)(N_EDGES + N_NODES) * 4);
    _Float16* wbuf = (_Float16*)alloc((size_t)(N_EDGES + N_NODES) * 4 * 2);
    int*      bsum = (int*)alloc(64 * 4);
    float*    sums = (float*)alloc(256 * 4);
    _Float16* WTh  = (_Float16*)alloc(128 * 128 * 2);
    float*    Wp   = (float*)alloc(128 * 128 * 4);
    float*    bp   = (float*)alloc(128 * 4);
    float*    g    = (float*)alloc(NGRAPHS * 128 * 4);
    float*    g2   = (float*)alloc(NGRAPHS * 128 * 4);
    float*    Wpc  = (float*)alloc(128 * 10 * 4);
    float*    bpc  = (float*)alloc(64);

    const int* esrc = ei;
    const int* edst = ei + N_EDGES;
    const int nb = divup(N_NODES, 1024);  // 49

    // ---- CSR build (deg starts at 1: self-loop per node) ----
    fill_i32<<<divup(N_NODES, 256), 256, 0, stream>>>(deg, 1, N_NODES);
    count_edges<<<divup(N_EDGES, 256), 256, 0, stream>>>(edst, deg, N_EDGES);
    scan_blocks<<<nb, 1024, 0, stream>>>(deg, rowp, bsum, N_NODES);
    scan_sums<<<1, 64, 0, stream>>>(bsum, nb);
    scan_add<<<divup(N_NODES, 256), 256, 0, stream>>>(rowp, curs, bsum, N_NODES, nb);
    scatter_edges<<<divup(N_EDGES, 256), 256, 0, stream>>>(esrc, edst, curs, col, N_EDGES);
    scatter_loops<<<divup(N_NODES, 256), 256, 0, stream>>>(curs, col, sums, N_NODES);

    // ---- h = relu(BN(x) @ w_feat) ----
    cast_f32_f16<<<divup(N_NODES * 32, 256), 256, 0, stream>>>(x, xh, N_NODES * 32);
    colstats<<<512, 128, 0, stream>>>(x, N_NODES, sums);
    fold_t<<<1, 128, 0, stream>>>(sums, 1.f / N_NODES, bnf_g, bnf_b, w_feat, WTh, bp);
    gemm_mfma<<<divup(N_NODES, 64), 256, 0, stream>>>(xh, WTh, bp, h, N_NODES, 1,
                                                      nullptr, nullptr, nullptr, nullptr, sums);

    // ---- 3 GAT conv layers ----
    for (int i = 0; i < NCONV; ++i) {
        colstats_h<<<512, 128, 0, stream>>>(h, N_NODES, sums);
        fold_t<<<1, 128, 0, stream>>>(sums, 1.f / N_NODES, bnc_g + 128 * i, bnc_b + 128 * i,
                                      gat_w + 16384 * i, WTh, bp);
        gemm_mfma<<<divup(N_NODES, 64), 256, 0, stream>>>(h, WTh, bp, hp, N_NODES, 0,
                                                          gat_as + 128 * i, gat_ad + 128 * i,
                                                          als, ald, sums);
        gat_aggregate<<<divup(N_NODES, 4), 256, 0, stream>>>(hp, als, ald, rowp, col,
                                                             gat_b + 128 * i, h, wbuf, g, N_NODES);
    }

    // ---- pool + MLP head ----
    pool_kernel<<<divup(N_NODES, 256), 128, 0, stream>>>(h, batch, g, N_NODES, 256);
    colstats_small<<<1, 128, 0, stream>>>(g, NGRAPHS, sums);
    fold_kernel<<<1, 128, 0, stream>>>(sums, 1.f / NGRAPHS, bnfc_g, bnfc_b, lin_w, lin_b, Wp, bp);
    gemm128<<<divup(NGRAPHS, 32), 256, 0, stream>>>(g, Wp, bp, g2, NGRAPHS, 1);
    colstats_small<<<1, 128, 0, stream>>>(g2, NGRAPHS, sums);
    fold_cls<<<1, 128, 0, stream>>>(sums, 1.f / NGRAPHS, bnh_g, bnh_b, cls_w, cls_b, Wpc, bpc);
    final_kernel<<<divup(NGRAPHS, 64), 64, 0, stream>>>(g2, Wpc, bpc, out, NGRAPHS);
}

// Round 4
// 493.756 us; speedup vs baseline: 2.3169x; 1.6257x over previous
//
#include <hip/hip_runtime.h>
#include <math.h>

#define N_NODES 50000
#define N_EDGES 800000
#define NGRAPHS 256
#define NCONV 3

typedef _Float16 h4 __attribute__((ext_vector_type(4)));
typedef _Float16 h8 __attribute__((ext_vector_type(8)));
typedef float f32x4 __attribute__((ext_vector_type(4)));

static inline int divup(int a, int b) { return (a + b - 1) / b; }

__global__ void fill_i32(int* p, int v, int n) {
    int i = blockIdx.x * blockDim.x + threadIdx.x;
    if (i < n) p[i] = v;
}

// ---------------- CSR build ----------------
__global__ void count_edges(const int* __restrict__ dst, int* __restrict__ deg, int E) {
    int i = blockIdx.x * blockDim.x + threadIdx.x;
    if (i < E) atomicAdd(&deg[dst[i]], 1);
}

__global__ __launch_bounds__(1024) void scan_blocks(const int* __restrict__ deg,
                                                    int* __restrict__ excl,
                                                    int* __restrict__ bsum, int n) {
    __shared__ int buf[1024];
    int tid = threadIdx.x;
    int i = blockIdx.x * 1024 + tid;
    int v = (i < n) ? deg[i] : 0;
    buf[tid] = v;
    __syncthreads();
    for (int off = 1; off < 1024; off <<= 1) {
        int t = (tid >= off) ? buf[tid - off] : 0;
        __syncthreads();
        buf[tid] += t;
        __syncthreads();
    }
    if (i < n) excl[i] = buf[tid] - v;
    if (tid == 1023) bsum[blockIdx.x] = buf[1023];
}

__global__ void scan_sums(int* __restrict__ bsum, int nb) {
    int tid = threadIdx.x;  // 64
    int orig = (tid < nb) ? bsum[tid] : 0;
    int v = orig;
    for (int off = 1; off < 64; off <<= 1) {
        int t = __shfl_up(v, off, 64);
        if (tid >= off) v += t;
    }
    if (tid < nb) bsum[tid] = v - orig;
    if (tid == nb - 1) bsum[nb] = v;
}

__global__ void scan_add(int* __restrict__ row_ptr, int* __restrict__ cursor,
                         const int* __restrict__ bsum, int n, int nb) {
    int i = blockIdx.x * blockDim.x + threadIdx.x;
    if (i < n) {
        int v = row_ptr[i] + bsum[i >> 10];
        row_ptr[i] = v;
        cursor[i] = v;
    }
    if (i == 0) row_ptr[n] = bsum[nb];
}

__global__ void scatter_edges(const int* __restrict__ src, const int* __restrict__ dst,
                              int* __restrict__ cursor, int* __restrict__ col, int E) {
    int i = blockIdx.x * blockDim.x + threadIdx.x;
    if (i < E) {
        int d = dst[i];
        int p = atomicAdd(&cursor[d], 1);
        col[p] = src[i];
    }
}

// also zeroes sums[0..511] (runs before first stats)
__global__ void scatter_loops(int* __restrict__ cursor, int* __restrict__ col,
                              float* __restrict__ sums, int n) {
    if (blockIdx.x == 0 && threadIdx.x < 256) {
        sums[threadIdx.x] = 0.f;
        sums[256 + threadIdx.x] = 0.f;
    }
    int v = blockIdx.x * blockDim.x + threadIdx.x;
    if (v < n) {
        int p = atomicAdd(&cursor[v], 1);
        col[p] = v;
    }
}

// ---------------- fused cast f32->f16 + column stats ----------------
// 16 threads/row, 8 cols each (2x float4 loads), 16 rows in flight per block.
__global__ __launch_bounds__(256) void cast_stats(const float* __restrict__ x,
                                                  _Float16* __restrict__ y, int n,
                                                  float* __restrict__ sums) {
    __shared__ float S[16][128], S2[16][128];
    int tid = threadIdx.x;
    int c8 = (tid & 15) * 8;
    int rg = tid >> 4;
    float s[8] = {}, s2[8] = {};
    for (int r = blockIdx.x * 16 + rg; r < n; r += gridDim.x * 16) {
        const float4* p = (const float4*)&x[(size_t)r * 128 + c8];
        float4 v0 = p[0], v1 = p[1];
        float f[8] = {v0.x, v0.y, v0.z, v0.w, v1.x, v1.y, v1.z, v1.w};
        h8 o;
#pragma unroll
        for (int i = 0; i < 8; ++i) {
            o[i] = (_Float16)f[i];
            s[i] += f[i];
            s2[i] += f[i] * f[i];
        }
        *(h8*)&y[(size_t)r * 128 + c8] = o;
    }
#pragma unroll
    for (int i = 0; i < 8; ++i) { S[rg][c8 + i] = s[i]; S2[rg][c8 + i] = s2[i]; }
    __syncthreads();
    if (tid < 128) {
        float a = 0.f, b = 0.f;
#pragma unroll
        for (int k = 0; k < 16; ++k) { a += S[k][tid]; b += S2[k][tid]; }
        atomicAdd(&sums[tid], a);
        atomicAdd(&sums[128 + tid], b);
    }
}

// ---------------- column stats, fp16 input ----------------
__global__ __launch_bounds__(256) void colstats_h(const _Float16* __restrict__ x, int n,
                                                  float* __restrict__ sums) {
    __shared__ float S[16][128], S2[16][128];
    int tid = threadIdx.x;
    int c8 = (tid & 15) * 8;
    int rg = tid >> 4;
    float s[8] = {}, s2[8] = {};
    for (int r = blockIdx.x * 16 + rg; r < n; r += gridDim.x * 16) {
        h8 v = *(const h8*)&x[(size_t)r * 128 + c8];
#pragma unroll
        for (int i = 0; i < 8; ++i) {
            float f = (float)v[i];
            s[i] += f;
            s2[i] += f * f;
        }
    }
#pragma unroll
    for (int i = 0; i < 8; ++i) { S[rg][c8 + i] = s[i]; S2[rg][c8 + i] = s2[i]; }
    __syncthreads();
    if (tid < 128) {
        float a = 0.f, b = 0.f;
#pragma unroll
        for (int k = 0; k < 16; ++k) { a += S[k][tid]; b += S2[k][tid]; }
        atomicAdd(&sums[tid], a);
        atomicAdd(&sums[128 + tid], b);
    }
}

// ---------------- small (rows<=256) column stats: 16 blocks x 256 threads ----------------
__global__ __launch_bounds__(256) void colstats_small16(const float* __restrict__ x, int rows,
                                                        float* __restrict__ sums) {
    __shared__ float S[16][128], S2[16][128];
    int tid = threadIdx.x;
    int c8 = (tid & 15) * 8;
    int rg = tid >> 4;
    float s[8] = {}, s2[8] = {};
    for (int r = blockIdx.x * 16 + rg; r < rows; r += gridDim.x * 16) {
        const float4* p = (const float4*)&x[(size_t)r * 128 + c8];
        float4 v0 = p[0], v1 = p[1];
        float f[8] = {v0.x, v0.y, v0.z, v0.w, v1.x, v1.y, v1.z, v1.w};
#pragma unroll
        for (int i = 0; i < 8; ++i) { s[i] += f[i]; s2[i] += f[i] * f[i]; }
    }
#pragma unroll
    for (int i = 0; i < 8; ++i) { S[rg][c8 + i] = s[i]; S2[rg][c8 + i] = s2[i]; }
    __syncthreads();
    if (tid < 128) {
        float a = 0.f, b = 0.f;
#pragma unroll
        for (int k = 0; k < 16; ++k) { a += S[k][tid]; b += S2[k][tid]; }
        atomicAdd(&sums[tid], a);
        atomicAdd(&sums[128 + tid], b);
    }
}

// ---------------- BN folds (parallel: 128 blocks, one output row each) ----------------
// WTh[j][k] = half(s[k]*W[k][j]); bp[j] = sum_k t[k]W[k][j]
__global__ __launch_bounds__(128) void fold_t(const float* __restrict__ sums, float inv_n,
                                              const float* __restrict__ gamma,
                                              const float* __restrict__ beta,
                                              const float* __restrict__ W,
                                              _Float16* __restrict__ WTh, float* __restrict__ bp) {
    int j = blockIdx.x, k = threadIdx.x;
    float mean = sums[k] * inv_n;
    float var = sums[128 + k] * inv_n - mean * mean;
    float sc = gamma[k] * rsqrtf(var + 1e-5f);
    float t = beta[k] - mean * sc;
    float w = W[k * 128 + j];
    WTh[j * 128 + k] = (_Float16)(sc * w);
    float pb = t * w;
    for (int off = 1; off < 64; off <<= 1) pb += __shfl_xor(pb, off, 64);
    __shared__ float r2[2];
    if ((k & 63) == 0) r2[k >> 6] = pb;
    __syncthreads();
    if (k == 0) bp[j] = r2[0] + r2[1];
}

// f32 non-transposed fold for head gemm: Wp[k][j] = s[k]W[k][j]; bp[j]=extra[j]+sum_k t[k]W[k][j]
__global__ __launch_bounds__(128) void fold_head(const float* __restrict__ sums, float inv_n,
                                                 const float* __restrict__ gamma,
                                                 const float* __restrict__ beta,
                                                 const float* __restrict__ W,
                                                 const float* __restrict__ extra,
                                                 float* __restrict__ Wp, float* __restrict__ bp) {
    int j = blockIdx.x, k = threadIdx.x;
    float mean = sums[k] * inv_n;
    float var = sums[128 + k] * inv_n - mean * mean;
    float sc = gamma[k] * rsqrtf(var + 1e-5f);
    float t = beta[k] - mean * sc;
    float w = W[k * 128 + j];
    Wp[k * 128 + j] = sc * w;
    float pb = t * w;
    for (int off = 1; off < 64; off <<= 1) pb += __shfl_xor(pb, off, 64);
    __shared__ float r2[2];
    if ((k & 63) == 0) r2[k >> 6] = pb;
    __syncthreads();
    if (k == 0) bp[j] = extra[j] + r2[0] + r2[1];
}

__global__ __launch_bounds__(128) void fold_cls(const float* __restrict__ sums, float inv_n,
                                                const float* __restrict__ gamma,
                                                const float* __restrict__ beta,
                                                const float* __restrict__ W,
                                                const float* __restrict__ b,
                                                float* __restrict__ Wp, float* __restrict__ bp) {
    __shared__ float sS[128], part[128][10];
    int k = threadIdx.x;
    float mean = sums[k] * inv_n;
    float var = sums[128 + k] * inv_n - mean * mean;
    float sc = gamma[k] * rsqrtf(var + 1e-5f);
    float t = beta[k] - mean * sc;
    sS[k] = sc;
#pragma unroll
    for (int j = 0; j < 10; ++j) part[k][j] = t * W[k * 10 + j];
    __syncthreads();
    for (int i = k; i < 1280; i += 128) Wp[i] = sS[i / 10] * W[i];
    if (k < 10) {
        float acc = b[k];
        for (int kk = 0; kk < 128; ++kk) acc += part[kk][k];
        bp[k] = acc;
    }
}

// ---------------- MFMA fp16 GEMM: out[n,128] = A[n,128] @ W'[128,128] + bp ----------------
__global__ __launch_bounds__(256) void gemm_mfma(const _Float16* __restrict__ Ah,
                                                 const _Float16* __restrict__ WTh,
                                                 const float* __restrict__ bp,
                                                 _Float16* __restrict__ outh, int n, int relu,
                                                 const float* __restrict__ asrc,
                                                 const float* __restrict__ adst,
                                                 float* __restrict__ als,
                                                 float* __restrict__ ald,
                                                 float* __restrict__ sums_zero) {
    __shared__ _Float16 Wl[128 * 136];  // +8 halves pad per row: conflict-free b128
    int tid = threadIdx.x;
    if (blockIdx.x == 0 && tid < 256 && sums_zero) sums_zero[tid] = 0.f;
    for (int i = tid; i < 2048; i += 256) {
        int r = i >> 4, s = i & 15;
        *(h8*)&Wl[r * 136 + s * 8] = *(const h8*)&WTh[r * 128 + s * 8];
    }
    __syncthreads();
    int lane = tid & 63, wid = tid >> 6;
    int m = lane & 15, quad = lane >> 4;
    int rbase = blockIdx.x * 64 + wid * 16;
    if (rbase >= n) return;

    const _Float16* arow = Ah + (size_t)(rbase + m) * 128 + quad * 8;
    h8 af0 = *(const h8*)(arow);
    h8 af1 = *(const h8*)(arow + 32);
    h8 af2 = *(const h8*)(arow + 64);
    h8 af3 = *(const h8*)(arow + 96);

    float ps[4][4] = {}, pd[4][4] = {};
    const bool do_al = (asrc != nullptr);

#pragma unroll
    for (int t = 0; t < 8; ++t) {
        const _Float16* wrow = &Wl[(t * 16 + m) * 136 + quad * 8];
        f32x4 acc = {0.f, 0.f, 0.f, 0.f};
        acc = __builtin_amdgcn_mfma_f32_16x16x32_f16(af0, *(const h8*)(wrow), acc, 0, 0, 0);
        acc = __builtin_amdgcn_mfma_f32_16x16x32_f16(af1, *(const h8*)(wrow + 32), acc, 0, 0, 0);
        acc = __builtin_amdgcn_mfma_f32_16x16x32_f16(af2, *(const h8*)(wrow + 64), acc, 0, 0, 0);
        acc = __builtin_amdgcn_mfma_f32_16x16x32_f16(af3, *(const h8*)(wrow + 96), acc, 0, 0, 0);
        int j = t * 16 + m;
        float bj = bp[j];
        float avs = 0.f, avd = 0.f;
        if (do_al) { avs = asrc[j]; avd = adst[j]; }
        int hh = t >> 1;
#pragma unroll
        for (int r = 0; r < 4; ++r) {
            float o = acc[r] + bj;
            if (do_al) {
                ps[r][hh] += o * avs;
                pd[r][hh] += o * avd;
            }
            float v = relu ? fmaxf(o, 0.f) : o;
            int row = rbase + quad * 4 + r;
            outh[(size_t)row * 128 + j] = (_Float16)v;
        }
    }
    if (do_al) {
#pragma unroll
        for (int r = 0; r < 4; ++r) {
#pragma unroll
            for (int hh = 0; hh < 4; ++hh) {
                float v = ps[r][hh];
                v += __shfl_xor(v, 1, 64); v += __shfl_xor(v, 2, 64);
                v += __shfl_xor(v, 4, 64); v += __shfl_xor(v, 8, 64);
                float w = pd[r][hh];
                w += __shfl_xor(w, 1, 64); w += __shfl_xor(w, 2, 64);
                w += __shfl_xor(w, 4, 64); w += __shfl_xor(w, 8, 64);
                if (m == 0) {
                    int row = rbase + quad * 4 + r;
                    als[row * 4 + hh] = v;
                    ald[row * 4 + hh] = w;
                }
            }
        }
    }
}

__device__ __forceinline__ float leaky(float x) { return fmaxf(x, 0.2f * x); }

// ---------------- GAT aggregation: one wave per dst node, 2 passes ----------------
__global__ __launch_bounds__(256) void gat_aggregate(const _Float16* __restrict__ hp,
                                                     const float* __restrict__ al_s,
                                                     const float* __restrict__ al_d,
                                                     const int* __restrict__ row_ptr,
                                                     const int* __restrict__ col,
                                                     const float* __restrict__ bias,
                                                     _Float16* __restrict__ h_out,
                                                     _Float16* __restrict__ wbuf,
                                                     float* __restrict__ g_zero, int n) {
    if (blockIdx.x < 128) g_zero[blockIdx.x * 256 + threadIdx.x] = 0.f;
    int lane = threadIdx.x & 63;
    int node = blockIdx.x * 4 + (threadIdx.x >> 6);
    if (node >= n) return;
    int beg = row_ptr[node], end = row_ptr[node + 1];
    float4 ad = *(const float4*)&al_d[node * 4];
    float4 c;
    c.x = leaky(ad.x); c.y = leaky(ad.y); c.z = leaky(ad.z); c.w = leaky(ad.w);
    float s0 = 0.f, s1 = 0.f, s2 = 0.f, s3 = 0.f;
    for (int e = beg + lane; e < end; e += 64) {
        int s = col[e];
        float4 as = *(const float4*)&al_s[s * 4];
        float l0 = fminf(leaky(as.x + ad.x) - c.x, 30.f);
        float l1 = fminf(leaky(as.y + ad.y) - c.y, 30.f);
        float l2 = fminf(leaky(as.z + ad.z) - c.z, 30.f);
        float l3 = fminf(leaky(as.w + ad.w) - c.w, 30.f);
        h4 lh;
        lh[0] = (_Float16)l0; lh[1] = (_Float16)l1;
        lh[2] = (_Float16)l2; lh[3] = (_Float16)l3;
        *(h4*)&wbuf[(size_t)e * 4] = lh;
        s0 += expf((float)lh[0]); s1 += expf((float)lh[1]);
        s2 += expf((float)lh[2]); s3 += expf((float)lh[3]);
    }
    for (int off = 32; off >= 1; off >>= 1) {
        s0 += __shfl_xor(s0, off, 64);
        s1 += __shfl_xor(s1, off, 64);
        s2 += __shfl_xor(s2, off, 64);
        s3 += __shfl_xor(s3, off, 64);
    }
    float d0 = 1.f / (s0 + 1e-16f), d1 = 1.f / (s1 + 1e-16f);
    float d2 = 1.f / (s2 + 1e-16f), d3 = 1.f / (s3 + 1e-16f);
    __threadfence_block();
    int q = lane >> 4, l4 = lane & 15;
    int f0 = l4 * 8;
    int head = l4 >> 2;
    float dh = head == 0 ? d0 : head == 1 ? d1 : head == 2 ? d2 : d3;
    float a0 = 0.f, a1 = 0.f, a2 = 0.f, a3 = 0.f, a4 = 0.f, a5 = 0.f, a6 = 0.f, a7 = 0.f;
    for (int e = beg + q; e < end; e += 4) {
        int s = col[e];
        float w = expf((float)wbuf[(size_t)e * 4 + head]) * dh;
        h8 hv = *(const h8*)&hp[(size_t)s * 128 + f0];
        a0 += (float)hv[0] * w; a1 += (float)hv[1] * w;
        a2 += (float)hv[2] * w; a3 += (float)hv[3] * w;
        a4 += (float)hv[4] * w; a5 += (float)hv[5] * w;
        a6 += (float)hv[6] * w; a7 += (float)hv[7] * w;
    }
#pragma unroll
    for (int off = 16; off <= 32; off <<= 1) {
        a0 += __shfl_xor(a0, off, 64); a1 += __shfl_xor(a1, off, 64);
        a2 += __shfl_xor(a2, off, 64); a3 += __shfl_xor(a3, off, 64);
        a4 += __shfl_xor(a4, off, 64); a5 += __shfl_xor(a5, off, 64);
        a6 += __shfl_xor(a6, off, 64); a7 += __shfl_xor(a7, off, 64);
    }
    if (q == 0) {
        float4 b0 = *(const float4*)&bias[f0];
        float4 b1 = *(const float4*)&bias[f0 + 4];
        h8 ov;
        ov[0] = (_Float16)fmaxf(a0 + b0.x, 0.f);
        ov[1] = (_Float16)fmaxf(a1 + b0.y, 0.f);
        ov[2] = (_Float16)fmaxf(a2 + b0.z, 0.f);
        ov[3] = (_Float16)fmaxf(a3 + b0.w, 0.f);
        ov[4] = (_Float16)fmaxf(a4 + b1.x, 0.f);
        ov[5] = (_Float16)fmaxf(a5 + b1.y, 0.f);
        ov[6] = (_Float16)fmaxf(a6 + b1.z, 0.f);
        ov[7] = (_Float16)fmaxf(a7 + b1.w, 0.f);
        *(h8*)&h_out[(size_t)node * 128 + f0] = ov;
    }
}

// ---------------- pooling (batch sorted), chunk=32 ----------------
__global__ void pool_kernel(const _Float16* __restrict__ h, const int* __restrict__ batch,
                            float* __restrict__ g, int n, int chunk) {
    int f = threadIdx.x;  // 128
    int a = blockIdx.x * chunk;
    if (a >= n) return;
    int b = min(n, a + chunk);
    float acc = 0.f;
    int cur = batch[a];
    for (int i = a; i < b; ++i) {
        int bi = batch[i];
        if (bi != cur) {
            atomicAdd(&g[cur * 128 + f], acc);
            acc = 0.f;
            cur = bi;
        }
        acc += (float)h[(size_t)i * 128 + f];
    }
    atomicAdd(&g[cur * 128 + f], acc);
}

// ---------------- head GEMM (f32, n=256) ----------------
__global__ __launch_bounds__(256) void gemm128(const float* __restrict__ A,
                                               const float* __restrict__ Wp,
                                               const float* __restrict__ bp,
                                               float* __restrict__ out, int n, int relu) {
    __shared__ float Wl[128 * 128];
    __shared__ float hT[128 * 32];
    int tid = threadIdx.x;
    for (int i = tid; i < 4096; i += 256) {
        ((float4*)Wl)[i] = ((const float4*)Wp)[i];
    }
    int base = blockIdx.x * 32;
    for (int pass = 0; pass < 4; ++pass) {
        int r = (tid >> 5) + pass * 8;
        int c4 = tid & 31;
        int row = base + r;
        float4 v = (row < n) ? ((const float4*)(A + (size_t)row * 128))[c4]
                             : make_float4(0.f, 0.f, 0.f, 0.f);
        hT[(c4 * 4 + 0) * 32 + r] = v.x;
        hT[(c4 * 4 + 1) * 32 + r] = v.y;
        hT[(c4 * 4 + 2) * 32 + r] = v.z;
        hT[(c4 * 4 + 3) * 32 + r] = v.w;
    }
    __syncthreads();
    int tx = tid & 31, ty = tid >> 5;
    int j0 = tx * 4, r0 = ty * 4;
    float acc[4][4] = {};
#pragma unroll 8
    for (int k = 0; k < 128; ++k) {
        float4 a = *(const float4*)&hT[k * 32 + r0];
        float4 w = *(const float4*)&Wl[k * 128 + j0];
        acc[0][0] += a.x * w.x; acc[0][1] += a.x * w.y; acc[0][2] += a.x * w.z; acc[0][3] += a.x * w.w;
        acc[1][0] += a.y * w.x; acc[1][1] += a.y * w.y; acc[1][2] += a.y * w.z; acc[1][3] += a.y * w.w;
        acc[2][0] += a.z * w.x; acc[2][1] += a.z * w.y; acc[2][2] += a.z * w.z; acc[2][3] += a.z * w.w;
        acc[3][0] += a.w * w.x; acc[3][1] += a.w * w.y; acc[3][2] += a.w * w.z; acc[3][3] += a.w * w.w;
    }
    float4 bb = *(const float4*)&bp[j0];
    for (int i2 = 0; i2 < 4; ++i2) {
        int row = base + r0 + i2;
        if (row < n) {
            float4 o = make_float4(acc[i2][0] + bb.x, acc[i2][1] + bb.y,
                                   acc[i2][2] + bb.z, acc[i2][3] + bb.w);
            if (relu) {
                o.x = fmaxf(o.x, 0.f); o.y = fmaxf(o.y, 0.f);
                o.z = fmaxf(o.z, 0.f); o.w = fmaxf(o.w, 0.f);
            }
            *(float4*)&out[(size_t)row * 128 + j0] = o;
        }
    }
}

// ---------------- final classifier + log_softmax (one wave per row) ----------------
__global__ __launch_bounds__(64) void final_kernel(const float* __restrict__ g2,
                                                   const float* __restrict__ Wpc,
                                                   const float* __restrict__ bpc,
                                                   float* __restrict__ out, int rows) {
    int r = blockIdx.x;
    if (r >= rows) return;
    int lane = threadIdx.x;
    float logit[10] = {};
    for (int k = lane; k < 128; k += 64) {
        float gv = g2[r * 128 + k];
#pragma unroll
        for (int j = 0; j < 10; ++j) logit[j] += gv * Wpc[k * 10 + j];
    }
#pragma unroll
    for (int j = 0; j < 10; ++j)
        for (int off = 1; off < 64; off <<= 1) logit[j] += __shfl_xor(logit[j], off, 64);
    if (lane == 0) {
        float m = -1e30f;
#pragma unroll
        for (int j = 0; j < 10; ++j) { logit[j] += bpc[j]; m = fmaxf(m, logit[j]); }
        float sum = 0.f;
#pragma unroll
        for (int j = 0; j < 10; ++j) sum += expf(logit[j] - m);
        float lse = m + logf(sum);
#pragma unroll
        for (int j = 0; j < 10; ++j) out[r * 10 + j] = logit[j] - lse;
    }
}

extern "C" void kernel_launch(void* const* d_in, const int* in_sizes, int n_in,
                              void* d_out, int out_size, void* d_ws, size_t ws_size,
                              hipStream_t stream) {
    const float* x      = (const float*)d_in[0];
    const int*   ei     = (const int*)d_in[1];
    const int*   batch  = (const int*)d_in[2];
    const float* w_feat = (const float*)d_in[3];
    const float* bnf_g  = (const float*)d_in[4];
    const float* bnf_b  = (const float*)d_in[5];
    const float* bnc_g  = (const float*)d_in[6];
    const float* bnc_b  = (const float*)d_in[7];
    const float* gat_w  = (const float*)d_in[8];
    const float* gat_as = (const float*)d_in[9];
    const float* gat_ad = (const float*)d_in[10];
    const float* gat_b  = (const float*)d_in[11];
    const float* bnfc_g = (const float*)d_in[12];
    const float* bnfc_b = (const float*)d_in[13];
    const float* lin_w  = (const float*)d_in[14];
    const float* lin_b  = (const float*)d_in[15];
    const float* bnh_g  = (const float*)d_in[16];
    const float* bnh_b  = (const float*)d_in[17];
    const float* cls_w  = (const float*)d_in[18];
    const float* cls_b  = (const float*)d_in[19];
    float* out = (float*)d_out;

    char* ws = (char*)d_ws;
    size_t off = 0;
    auto alloc = [&](size_t bytes) -> void* {
        void* p = ws + off;
        off = (off + bytes + 255) & ~(size_t)255;
        return p;
    };
    _Float16* xh   = (_Float16*)alloc((size_t)N_NODES * 128 * 2);
    _Float16* h    = (_Float16*)alloc((size_t)N_NODES * 128 * 2);
    _Float16* hp   = (_Float16*)alloc((size_t)N_NODES * 128 * 2);
    float*    als  = (float*)alloc((size_t)N_NODES * 4 * 4);
    float*    ald  = (float*)alloc((size_t)N_NODES * 4 * 4);
    int*      deg  = (int*)alloc((size_t)N_NODES * 4);
    int*      curs = (int*)alloc((size_t)N_NODES * 4);
    int*      rowp = (int*)alloc((size_t)(N_NODES + 1) * 4);
    int*      col  = (int*)alloc((size_t)(N_EDGES + N_NODES) * 4);
    _Float16* wbuf = (_Float16*)alloc((size_t)(N_EDGES + N_NODES) * 4 * 2);
    int*      bsum = (int*)alloc(64 * 4);
    float*    sums = (float*)alloc(512 * 4);    // [0..255] big-path stats, [256..511] head stats
    _Float16* WTh  = (_Float16*)alloc(128 * 128 * 2);
    float*    Wp   = (float*)alloc(128 * 128 * 4);
    float*    bp   = (float*)alloc(128 * 4);
    float*    g    = (float*)alloc(NGRAPHS * 128 * 4);
    float*    g2   = (float*)alloc(NGRAPHS * 128 * 4);
    float*    Wpc  = (float*)alloc(128 * 10 * 4);
    float*    bpc  = (float*)alloc(64);

    const int* esrc = ei;
    const int* edst = ei + N_EDGES;
    const int nb = divup(N_NODES, 1024);  // 49

    // ---- CSR build (deg starts at 1: self-loop per node) ----
    fill_i32<<<divup(N_NODES, 256), 256, 0, stream>>>(deg, 1, N_NODES);
    count_edges<<<divup(N_EDGES, 256), 256, 0, stream>>>(edst, deg, N_EDGES);
    scan_blocks<<<nb, 1024, 0, stream>>>(deg, rowp, bsum, N_NODES);
    scan_sums<<<1, 64, 0, stream>>>(bsum, nb);
    scan_add<<<divup(N_NODES, 256), 256, 0, stream>>>(rowp, curs, bsum, N_NODES, nb);
    scatter_edges<<<divup(N_EDGES, 256), 256, 0, stream>>>(esrc, edst, curs, col, N_EDGES);
    scatter_loops<<<divup(N_NODES, 256), 256, 0, stream>>>(curs, col, sums, N_NODES);

    // ---- h = relu(BN(x) @ w_feat) ----
    cast_stats<<<256, 256, 0, stream>>>(x, xh, N_NODES, sums);
    fold_t<<<128, 128, 0, stream>>>(sums, 1.f / N_NODES, bnf_g, bnf_b, w_feat, WTh, bp);
    gemm_mfma<<<divup(N_NODES, 64), 256, 0, stream>>>(xh, WTh, bp, h, N_NODES, 1,
                                                      nullptr, nullptr, nullptr, nullptr, sums);

    // ---- 3 GAT conv layers ----
    for (int i = 0; i < NCONV; ++i) {
        colstats_h<<<256, 256, 0, stream>>>(h, N_NODES, sums);
        fold_t<<<128, 128, 0, stream>>>(sums, 1.f / N_NODES, bnc_g + 128 * i, bnc_b + 128 * i,
                                        gat_w + 16384 * i, WTh, bp);
        gemm_mfma<<<divup(N_NODES, 64), 256, 0, stream>>>(h, WTh, bp, hp, N_NODES, 0,
                                                          gat_as + 128 * i, gat_ad + 128 * i,
                                                          als, ald, sums);
        gat_aggregate<<<divup(N_NODES, 4), 256, 0, stream>>>(hp, als, ald, rowp, col,
                                                             gat_b + 128 * i, h, wbuf, g, N_NODES);
    }

    // ---- pool + MLP head ----
    pool_kernel<<<divup(N_NODES, 32), 128, 0, stream>>>(h, batch, g, N_NODES, 32);
    colstats_small16<<<16, 256, 0, stream>>>(g, NGRAPHS, sums);           // into sums[0..255] (zeroed by last gemm_mfma)
    fold_head<<<128, 128, 0, stream>>>(sums, 1.f / NGRAPHS, bnfc_g, bnfc_b, lin_w, lin_b, Wp, bp);
    gemm128<<<divup(NGRAPHS, 32), 256, 0, stream>>>(g, Wp, bp, g2, NGRAPHS, 1);
    colstats_small16<<<16, 256, 0, stream>>>(g2, NGRAPHS, sums + 256);    // into sums[256..511] (zeroed by scatter_loops)
    fold_cls<<<1, 128, 0, stream>>>(sums + 256, 1.f / NGRAPHS, bnh_g, bnh_b, cls_w, cls_b, Wpc, bpc);
    final_kernel<<<NGRAPHS, 64, 0, stream>>>(g2, Wpc, bpc, out, NGRAPHS);
}

// Round 5
// 475.618 us; speedup vs baseline: 2.4053x; 1.0381x over previous
//
#include <hip/hip_runtime.h>
#include <math.h>

#define N_NODES 50000
#define N_EDGES 800000
#define NGRAPHS 256
#define NCONV 3
#define SCAT_CHUNK 2048

typedef _Float16 h4 __attribute__((ext_vector_type(4)));
typedef _Float16 h8 __attribute__((ext_vector_type(8)));
typedef float f32x4 __attribute__((ext_vector_type(4)));

static inline int divup(int a, int b) { return (a + b - 1) / b; }

__global__ void fill_i32(int* p, int v, int n) {
    int i = blockIdx.x * blockDim.x + threadIdx.x;
    if (i < n) p[i] = v;
}

// ---------------- CSR build ----------------
__global__ void count_edges(const int* __restrict__ dst, int* __restrict__ deg, int E) {
    int i = blockIdx.x * blockDim.x + threadIdx.x;
    if (i < E) atomicAdd(&deg[dst[i]], 1);
}

__global__ __launch_bounds__(1024) void scan_blocks(const int* __restrict__ deg,
                                                    int* __restrict__ excl,
                                                    int* __restrict__ bsum, int n) {
    __shared__ int buf[1024];
    int tid = threadIdx.x;
    int i = blockIdx.x * 1024 + tid;
    int v = (i < n) ? deg[i] : 0;
    buf[tid] = v;
    __syncthreads();
    for (int off = 1; off < 1024; off <<= 1) {
        int t = (tid >= off) ? buf[tid - off] : 0;
        __syncthreads();
        buf[tid] += t;
        __syncthreads();
    }
    if (i < n) excl[i] = buf[tid] - v;
    if (tid == 1023) bsum[blockIdx.x] = buf[1023];
}

__global__ void scan_sums(int* __restrict__ bsum, int nb) {
    int tid = threadIdx.x;  // 64
    int orig = (tid < nb) ? bsum[tid] : 0;
    int v = orig;
    for (int off = 1; off < 64; off <<= 1) {
        int t = __shfl_up(v, off, 64);
        if (tid >= off) v += t;
    }
    if (tid < nb) bsum[tid] = v - orig;
    if (tid == nb - 1) bsum[nb] = v;
}

__global__ void scan_add(int* __restrict__ row_ptr, int* __restrict__ cursor,
                         const int* __restrict__ bsum, int n, int nb) {
    int i = blockIdx.x * blockDim.x + threadIdx.x;
    if (i < n) {
        int v = row_ptr[i] + bsum[i >> 10];
        row_ptr[i] = v;
        cursor[i] = v;
    }
    if (i == 0) row_ptr[n] = bsum[nb];
}

// XCD-sliced scatter: block (chunk c, slice x=blockIdx&7) reads chunk c of the edge
// list and scatters only edges whose dst lies in node-slice x. With round-robin
// blockIdx->XCD dispatch, all writes to a col line come from one XCD: kills the
// 16x write amplification + cross-XCD ping-pong. Correct regardless of placement.
__global__ __launch_bounds__(256) void scatter_edges_xcd(const int* __restrict__ src,
                                                         const int* __restrict__ dst,
                                                         int* __restrict__ cursor,
                                                         int* __restrict__ col, int E) {
    int slice = blockIdx.x & 7;
    int base = (blockIdx.x >> 3) * SCAT_CHUNK;
    int lim = min(base + SCAT_CHUNK, E);
    int lo = slice * (N_NODES / 8);
    int hi = lo + (N_NODES / 8);
    for (int i = base + threadIdx.x; i < lim; i += 256) {
        int d = dst[i];
        if (d >= lo && d < hi) {
            int p = atomicAdd(&cursor[d], 1);
            col[p] = src[i];
        }
    }
}

// also zeroes sums[0..511] (runs before first stats)
__global__ void scatter_loops(int* __restrict__ cursor, int* __restrict__ col,
                              float* __restrict__ sums, int n) {
    if (blockIdx.x == 0 && threadIdx.x < 256) {
        sums[threadIdx.x] = 0.f;
        sums[256 + threadIdx.x] = 0.f;
    }
    int v = blockIdx.x * blockDim.x + threadIdx.x;
    if (v < n) {
        int p = atomicAdd(&cursor[v], 1);
        col[p] = v;
    }
}

// ---------------- fused cast f32->f16 + column stats ----------------
__global__ __launch_bounds__(256) void cast_stats(const float* __restrict__ x,
                                                  _Float16* __restrict__ y, int n,
                                                  float* __restrict__ sums) {
    __shared__ float S[16][128], S2[16][128];
    int tid = threadIdx.x;
    int c8 = (tid & 15) * 8;
    int rg = tid >> 4;
    float s[8] = {}, s2[8] = {};
    for (int r = blockIdx.x * 16 + rg; r < n; r += gridDim.x * 16) {
        const float4* p = (const float4*)&x[(size_t)r * 128 + c8];
        float4 v0 = p[0], v1 = p[1];
        float f[8] = {v0.x, v0.y, v0.z, v0.w, v1.x, v1.y, v1.z, v1.w};
        h8 o;
#pragma unroll
        for (int i = 0; i < 8; ++i) {
            o[i] = (_Float16)f[i];
            s[i] += f[i];
            s2[i] += f[i] * f[i];
        }
        *(h8*)&y[(size_t)r * 128 + c8] = o;
    }
#pragma unroll
    for (int i = 0; i < 8; ++i) { S[rg][c8 + i] = s[i]; S2[rg][c8 + i] = s2[i]; }
    __syncthreads();
    if (tid < 128) {
        float a = 0.f, b = 0.f;
#pragma unroll
        for (int k = 0; k < 16; ++k) { a += S[k][tid]; b += S2[k][tid]; }
        atomicAdd(&sums[tid], a);
        atomicAdd(&sums[128 + tid], b);
    }
}

// ---------------- column stats, fp16 input ----------------
__global__ __launch_bounds__(256) void colstats_h(const _Float16* __restrict__ x, int n,
                                                  float* __restrict__ sums) {
    __shared__ float S[16][128], S2[16][128];
    int tid = threadIdx.x;
    int c8 = (tid & 15) * 8;
    int rg = tid >> 4;
    float s[8] = {}, s2[8] = {};
    for (int r = blockIdx.x * 16 + rg; r < n; r += gridDim.x * 16) {
        h8 v = *(const h8*)&x[(size_t)r * 128 + c8];
#pragma unroll
        for (int i = 0; i < 8; ++i) {
            float f = (float)v[i];
            s[i] += f;
            s2[i] += f * f;
        }
    }
#pragma unroll
    for (int i = 0; i < 8; ++i) { S[rg][c8 + i] = s[i]; S2[rg][c8 + i] = s2[i]; }
    __syncthreads();
    if (tid < 128) {
        float a = 0.f, b = 0.f;
#pragma unroll
        for (int k = 0; k < 16; ++k) { a += S[k][tid]; b += S2[k][tid]; }
        atomicAdd(&sums[tid], a);
        atomicAdd(&sums[128 + tid], b);
    }
}

// ---------------- small (rows<=256) column stats ----------------
__global__ __launch_bounds__(256) void colstats_small16(const float* __restrict__ x, int rows,
                                                        float* __restrict__ sums) {
    __shared__ float S[16][128], S2[16][128];
    int tid = threadIdx.x;
    int c8 = (tid & 15) * 8;
    int rg = tid >> 4;
    float s[8] = {}, s2[8] = {};
    for (int r = blockIdx.x * 16 + rg; r < rows; r += gridDim.x * 16) {
        const float4* p = (const float4*)&x[(size_t)r * 128 + c8];
        float4 v0 = p[0], v1 = p[1];
        float f[8] = {v0.x, v0.y, v0.z, v0.w, v1.x, v1.y, v1.z, v1.w};
#pragma unroll
        for (int i = 0; i < 8; ++i) { s[i] += f[i]; s2[i] += f[i] * f[i]; }
    }
#pragma unroll
    for (int i = 0; i < 8; ++i) { S[rg][c8 + i] = s[i]; S2[rg][c8 + i] = s2[i]; }
    __syncthreads();
    if (tid < 128) {
        float a = 0.f, b = 0.f;
#pragma unroll
        for (int k = 0; k < 16; ++k) { a += S[k][tid]; b += S2[k][tid]; }
        atomicAdd(&sums[tid], a);
        atomicAdd(&sums[128 + tid], b);
    }
}

// ---------------- BN folds ----------------
__global__ __launch_bounds__(128) void fold_t(const float* __restrict__ sums, float inv_n,
                                              const float* __restrict__ gamma,
                                              const float* __restrict__ beta,
                                              const float* __restrict__ W,
                                              _Float16* __restrict__ WTh, float* __restrict__ bp) {
    int j = blockIdx.x, k = threadIdx.x;
    float mean = sums[k] * inv_n;
    float var = sums[128 + k] * inv_n - mean * mean;
    float sc = gamma[k] * rsqrtf(var + 1e-5f);
    float t = beta[k] - mean * sc;
    float w = W[k * 128 + j];
    WTh[j * 128 + k] = (_Float16)(sc * w);
    float pb = t * w;
    for (int off = 1; off < 64; off <<= 1) pb += __shfl_xor(pb, off, 64);
    __shared__ float r2[2];
    if ((k & 63) == 0) r2[k >> 6] = pb;
    __syncthreads();
    if (k == 0) bp[j] = r2[0] + r2[1];
}

__global__ __launch_bounds__(128) void fold_head(const float* __restrict__ sums, float inv_n,
                                                 const float* __restrict__ gamma,
                                                 const float* __restrict__ beta,
                                                 const float* __restrict__ W,
                                                 const float* __restrict__ extra,
                                                 float* __restrict__ Wp, float* __restrict__ bp) {
    int j = blockIdx.x, k = threadIdx.x;
    float mean = sums[k] * inv_n;
    float var = sums[128 + k] * inv_n - mean * mean;
    float sc = gamma[k] * rsqrtf(var + 1e-5f);
    float t = beta[k] - mean * sc;
    float w = W[k * 128 + j];
    Wp[k * 128 + j] = sc * w;
    float pb = t * w;
    for (int off = 1; off < 64; off <<= 1) pb += __shfl_xor(pb, off, 64);
    __shared__ float r2[2];
    if ((k & 63) == 0) r2[k >> 6] = pb;
    __syncthreads();
    if (k == 0) bp[j] = extra[j] + r2[0] + r2[1];
}

__global__ __launch_bounds__(128) void fold_cls(const float* __restrict__ sums, float inv_n,
                                                const float* __restrict__ gamma,
                                                const float* __restrict__ beta,
                                                const float* __restrict__ W,
                                                const float* __restrict__ b,
                                                float* __restrict__ Wp, float* __restrict__ bp) {
    __shared__ float sS[128], part[128][10];
    int k = threadIdx.x;
    float mean = sums[k] * inv_n;
    float var = sums[128 + k] * inv_n - mean * mean;
    float sc = gamma[k] * rsqrtf(var + 1e-5f);
    float t = beta[k] - mean * sc;
    sS[k] = sc;
#pragma unroll
    for (int j = 0; j < 10; ++j) part[k][j] = t * W[k * 10 + j];
    __syncthreads();
    for (int i = k; i < 1280; i += 128) Wp[i] = sS[i / 10] * W[i];
    if (k < 10) {
        float acc = b[k];
        for (int kk = 0; kk < 128; ++kk) acc += part[kk][k];
        bp[k] = acc;
    }
}

// ---------------- MFMA fp16 GEMM ----------------
__global__ __launch_bounds__(256) void gemm_mfma(const _Float16* __restrict__ Ah,
                                                 const _Float16* __restrict__ WTh,
                                                 const float* __restrict__ bp,
                                                 _Float16* __restrict__ outh, int n, int relu,
                                                 const float* __restrict__ asrc,
                                                 const float* __restrict__ adst,
                                                 float* __restrict__ als,
                                                 float* __restrict__ ald,
                                                 float* __restrict__ sums_zero) {
    __shared__ _Float16 Wl[128 * 136];
    int tid = threadIdx.x;
    if (blockIdx.x == 0 && tid < 256 && sums_zero) sums_zero[tid] = 0.f;
    for (int i = tid; i < 2048; i += 256) {
        int r = i >> 4, s = i & 15;
        *(h8*)&Wl[r * 136 + s * 8] = *(const h8*)&WTh[r * 128 + s * 8];
    }
    __syncthreads();
    int lane = tid & 63, wid = tid >> 6;
    int m = lane & 15, quad = lane >> 4;
    int rbase = blockIdx.x * 64 + wid * 16;
    if (rbase >= n) return;

    const _Float16* arow = Ah + (size_t)(rbase + m) * 128 + quad * 8;
    h8 af0 = *(const h8*)(arow);
    h8 af1 = *(const h8*)(arow + 32);
    h8 af2 = *(const h8*)(arow + 64);
    h8 af3 = *(const h8*)(arow + 96);

    float ps[4][4] = {}, pd[4][4] = {};
    const bool do_al = (asrc != nullptr);

#pragma unroll
    for (int t = 0; t < 8; ++t) {
        const _Float16* wrow = &Wl[(t * 16 + m) * 136 + quad * 8];
        f32x4 acc = {0.f, 0.f, 0.f, 0.f};
        acc = __builtin_amdgcn_mfma_f32_16x16x32_f16(af0, *(const h8*)(wrow), acc, 0, 0, 0);
        acc = __builtin_amdgcn_mfma_f32_16x16x32_f16(af1, *(const h8*)(wrow + 32), acc, 0, 0, 0);
        acc = __builtin_amdgcn_mfma_f32_16x16x32_f16(af2, *(const h8*)(wrow + 64), acc, 0, 0, 0);
        acc = __builtin_amdgcn_mfma_f32_16x16x32_f16(af3, *(const h8*)(wrow + 96), acc, 0, 0, 0);
        int j = t * 16 + m;
        float bj = bp[j];
        float avs = 0.f, avd = 0.f;
        if (do_al) { avs = asrc[j]; avd = adst[j]; }
        int hh = t >> 1;
#pragma unroll
        for (int r = 0; r < 4; ++r) {
            float o = acc[r] + bj;
            if (do_al) {
                ps[r][hh] += o * avs;
                pd[r][hh] += o * avd;
            }
            float v = relu ? fmaxf(o, 0.f) : o;
            int row = rbase + quad * 4 + r;
            outh[(size_t)row * 128 + j] = (_Float16)v;
        }
    }
    if (do_al) {
#pragma unroll
        for (int r = 0; r < 4; ++r) {
#pragma unroll
            for (int hh = 0; hh < 4; ++hh) {
                float v = ps[r][hh];
                v += __shfl_xor(v, 1, 64); v += __shfl_xor(v, 2, 64);
                v += __shfl_xor(v, 4, 64); v += __shfl_xor(v, 8, 64);
                float w = pd[r][hh];
                w += __shfl_xor(w, 1, 64); w += __shfl_xor(w, 2, 64);
                w += __shfl_xor(w, 4, 64); w += __shfl_xor(w, 8, 64);
                if (m == 0) {
                    int row = rbase + quad * 4 + r;
                    als[row * 4 + hh] = v;
                    ald[row * 4 + hh] = w;
                }
            }
        }
    }
}

__device__ __forceinline__ float leaky(float x) { return fmaxf(x, 0.2f * x); }

// ---------------- GAT aggregation ----------------
// pass A: gather al_s, compute shifted logits (clamp 10), store UNNORMALIZED fp16
//         exp-weights to wbuf, sum the fp16-rounded weights (exact normalization).
// pass B: 4 edges/iter x 16 feature-lanes; weight = wbuf * dh (no expf).
__global__ __launch_bounds__(256) void gat_aggregate(const _Float16* __restrict__ hp,
                                                     const float* __restrict__ al_s,
                                                     const float* __restrict__ al_d,
                                                     const int* __restrict__ row_ptr,
                                                     const int* __restrict__ col,
                                                     const float* __restrict__ bias,
                                                     _Float16* __restrict__ h_out,
                                                     _Float16* __restrict__ wbuf,
                                                     float* __restrict__ g_zero, int n) {
    if (blockIdx.x < 128) g_zero[blockIdx.x * 256 + threadIdx.x] = 0.f;
    int lane = threadIdx.x & 63;
    int node = blockIdx.x * 4 + (threadIdx.x >> 6);
    if (node >= n) return;
    int beg = row_ptr[node], end = row_ptr[node + 1];
    float4 ad = *(const float4*)&al_d[node * 4];
    float4 c;
    c.x = leaky(ad.x); c.y = leaky(ad.y); c.z = leaky(ad.z); c.w = leaky(ad.w);
    float s0 = 0.f, s1 = 0.f, s2 = 0.f, s3 = 0.f;
    for (int e = beg + lane; e < end; e += 64) {
        unsigned s = (unsigned)col[e];
        float4 as = *(const float4*)&al_s[s * 4];
        float w0 = __expf(fminf(leaky(as.x + ad.x) - c.x, 10.f));
        float w1 = __expf(fminf(leaky(as.y + ad.y) - c.y, 10.f));
        float w2 = __expf(fminf(leaky(as.z + ad.z) - c.z, 10.f));
        float w3 = __expf(fminf(leaky(as.w + ad.w) - c.w, 10.f));
        h4 wh;
        wh[0] = (_Float16)w0; wh[1] = (_Float16)w1;
        wh[2] = (_Float16)w2; wh[3] = (_Float16)w3;
        *(h4*)&wbuf[(size_t)e * 4] = wh;
        s0 += (float)wh[0]; s1 += (float)wh[1];
        s2 += (float)wh[2]; s3 += (float)wh[3];
    }
    for (int off = 32; off >= 1; off >>= 1) {
        s0 += __shfl_xor(s0, off, 64);
        s1 += __shfl_xor(s1, off, 64);
        s2 += __shfl_xor(s2, off, 64);
        s3 += __shfl_xor(s3, off, 64);
    }
    float d0 = 1.f / (s0 + 1e-16f), d1 = 1.f / (s1 + 1e-16f);
    float d2 = 1.f / (s2 + 1e-16f), d3 = 1.f / (s3 + 1e-16f);
    __threadfence_block();
    int q = lane >> 4, l4 = lane & 15;
    int f0 = l4 * 8;
    int head = l4 >> 2;
    float dh = head == 0 ? d0 : head == 1 ? d1 : head == 2 ? d2 : d3;
    const _Float16* hpf = hp + f0;
    float a0 = 0.f, a1 = 0.f, a2 = 0.f, a3 = 0.f, a4 = 0.f, a5 = 0.f, a6 = 0.f, a7 = 0.f;
    for (int e = beg + q; e < end; e += 4) {
        unsigned s = (unsigned)col[e];
        float w = (float)wbuf[(size_t)e * 4 + head] * dh;
        h8 hv = *(const h8*)(hpf + (size_t)s * 128);
        a0 += (float)hv[0] * w; a1 += (float)hv[1] * w;
        a2 += (float)hv[2] * w; a3 += (float)hv[3] * w;
        a4 += (float)hv[4] * w; a5 += (float)hv[5] * w;
        a6 += (float)hv[6] * w; a7 += (float)hv[7] * w;
    }
#pragma unroll
    for (int off = 16; off <= 32; off <<= 1) {
        a0 += __shfl_xor(a0, off, 64); a1 += __shfl_xor(a1, off, 64);
        a2 += __shfl_xor(a2, off, 64); a3 += __shfl_xor(a3, off, 64);
        a4 += __shfl_xor(a4, off, 64); a5 += __shfl_xor(a5, off, 64);
        a6 += __shfl_xor(a6, off, 64); a7 += __shfl_xor(a7, off, 64);
    }
    if (q == 0) {
        float4 b0 = *(const float4*)&bias[f0];
        float4 b1 = *(const float4*)&bias[f0 + 4];
        h8 ov;
        ov[0] = (_Float16)fmaxf(a0 + b0.x, 0.f);
        ov[1] = (_Float16)fmaxf(a1 + b0.y, 0.f);
        ov[2] = (_Float16)fmaxf(a2 + b0.z, 0.f);
        ov[3] = (_Float16)fmaxf(a3 + b0.w, 0.f);
        ov[4] = (_Float16)fmaxf(a4 + b1.x, 0.f);
        ov[5] = (_Float16)fmaxf(a5 + b1.y, 0.f);
        ov[6] = (_Float16)fmaxf(a6 + b1.z, 0.f);
        ov[7] = (_Float16)fmaxf(a7 + b1.w, 0.f);
        *(h8*)&h_out[(size_t)node * 128 + f0] = ov;
    }
}

// ---------------- pooling (batch sorted), chunk=32 ----------------
__global__ void pool_kernel(const _Float16* __restrict__ h, const int* __restrict__ batch,
                            float* __restrict__ g, int n, int chunk) {
    int f = threadIdx.x;  // 128
    int a = blockIdx.x * chunk;
    if (a >= n) return;
    int b = min(n, a + chunk);
    float acc = 0.f;
    int cur = batch[a];
    for (int i = a; i < b; ++i) {
        int bi = batch[i];
        if (bi != cur) {
            atomicAdd(&g[cur * 128 + f], acc);
            acc = 0.f;
            cur = bi;
        }
        acc += (float)h[(size_t)i * 128 + f];
    }
    atomicAdd(&g[cur * 128 + f], acc);
}

// ---------------- head GEMM (f32, n=256) ----------------
__global__ __launch_bounds__(256) void gemm128(const float* __restrict__ A,
                                               const float* __restrict__ Wp,
                                               const float* __restrict__ bp,
                                               float* __restrict__ out, int n, int relu) {
    __shared__ float Wl[128 * 128];
    __shared__ float hT[128 * 32];
    int tid = threadIdx.x;
    for (int i = tid; i < 4096; i += 256) {
        ((float4*)Wl)[i] = ((const float4*)Wp)[i];
    }
    int base = blockIdx.x * 32;
    for (int pass = 0; pass < 4; ++pass) {
        int r = (tid >> 5) + pass * 8;
        int c4 = tid & 31;
        int row = base + r;
        float4 v = (row < n) ? ((const float4*)(A + (size_t)row * 128))[c4]
                             : make_float4(0.f, 0.f, 0.f, 0.f);
        hT[(c4 * 4 + 0) * 32 + r] = v.x;
        hT[(c4 * 4 + 1) * 32 + r] = v.y;
        hT[(c4 * 4 + 2) * 32 + r] = v.z;
        hT[(c4 * 4 + 3) * 32 + r] = v.w;
    }
    __syncthreads();
    int tx = tid & 31, ty = tid >> 5;
    int j0 = tx * 4, r0 = ty * 4;
    float acc[4][4] = {};
#pragma unroll 8
    for (int k = 0; k < 128; ++k) {
        float4 a = *(const float4*)&hT[k * 32 + r0];
        float4 w = *(const float4*)&Wl[k * 128 + j0];
        acc[0][0] += a.x * w.x; acc[0][1] += a.x * w.y; acc[0][2] += a.x * w.z; acc[0][3] += a.x * w.w;
        acc[1][0] += a.y * w.x; acc[1][1] += a.y * w.y; acc[1][2] += a.y * w.z; acc[1][3] += a.y * w.w;
        acc[2][0] += a.z * w.x; acc[2][1] += a.z * w.y; acc[2][2] += a.z * w.z; acc[2][3] += a.z * w.w;
        acc[3][0] += a.w * w.x; acc[3][1] += a.w * w.y; acc[3][2] += a.w * w.z; acc[3][3] += a.w * w.w;
    }
    float4 bb = *(const float4*)&bp[j0];
    for (int i2 = 0; i2 < 4; ++i2) {
        int row = base + r0 + i2;
        if (row < n) {
            float4 o = make_float4(acc[i2][0] + bb.x, acc[i2][1] + bb.y,
                                   acc[i2][2] + bb.z, acc[i2][3] + bb.w);
            if (relu) {
                o.x = fmaxf(o.x, 0.f); o.y = fmaxf(o.y, 0.f);
                o.z = fmaxf(o.z, 0.f); o.w = fmaxf(o.w, 0.f);
            }
            *(float4*)&out[(size_t)row * 128 + j0] = o;
        }
    }
}

// ---------------- final classifier + log_softmax ----------------
__global__ __launch_bounds__(64) void final_kernel(const float* __restrict__ g2,
                                                   const float* __restrict__ Wpc,
                                                   const float* __restrict__ bpc,
                                                   float* __restrict__ out, int rows) {
    int r = blockIdx.x;
    if (r >= rows) return;
    int lane = threadIdx.x;
    float logit[10] = {};
    for (int k = lane; k < 128; k += 64) {
        float gv = g2[r * 128 + k];
#pragma unroll
        for (int j = 0; j < 10; ++j) logit[j] += gv * Wpc[k * 10 + j];
    }
#pragma unroll
    for (int j = 0; j < 10; ++j)
        for (int off = 1; off < 64; off <<= 1) logit[j] += __shfl_xor(logit[j], off, 64);
    if (lane == 0) {
        float m = -1e30f;
#pragma unroll
        for (int j = 0; j < 10; ++j) { logit[j] += bpc[j]; m = fmaxf(m, logit[j]); }
        float sum = 0.f;
#pragma unroll
        for (int j = 0; j < 10; ++j) sum += expf(logit[j] - m);
        float lse = m + logf(sum);
#pragma unroll
        for (int j = 0; j < 10; ++j) out[r * 10 + j] = logit[j] - lse;
    }
}

extern "C" void kernel_launch(void* const* d_in, const int* in_sizes, int n_in,
                              void* d_out, int out_size, void* d_ws, size_t ws_size,
                              hipStream_t stream) {
    const float* x      = (const float*)d_in[0];
    const int*   ei     = (const int*)d_in[1];
    const int*   batch  = (const int*)d_in[2];
    const float* w_feat = (const float*)d_in[3];
    const float* bnf_g  = (const float*)d_in[4];
    const float* bnf_b  = (const float*)d_in[5];
    const float* bnc_g  = (const float*)d_in[6];
    const float* bnc_b  = (const float*)d_in[7];
    const float* gat_w  = (const float*)d_in[8];
    const float* gat_as = (const float*)d_in[9];
    const float* gat_ad = (const float*)d_in[10];
    const float* gat_b  = (const float*)d_in[11];
    const float* bnfc_g = (const float*)d_in[12];
    const float* bnfc_b = (const float*)d_in[13];
    const float* lin_w  = (const float*)d_in[14];
    const float* lin_b  = (const float*)d_in[15];
    const float* bnh_g  = (const float*)d_in[16];
    const float* bnh_b  = (const float*)d_in[17];
    const float* cls_w  = (const float*)d_in[18];
    const float* cls_b  = (const float*)d_in[19];
    float* out = (float*)d_out;

    char* ws = (char*)d_ws;
    size_t off = 0;
    auto alloc = [&](size_t bytes) -> void* {
        void* p = ws + off;
        off = (off + bytes + 255) & ~(size_t)255;
        return p;
    };
    _Float16* xh   = (_Float16*)alloc((size_t)N_NODES * 128 * 2);
    _Float16* h    = (_Float16*)alloc((size_t)N_NODES * 128 * 2);
    _Float16* hp   = (_Float16*)alloc((size_t)N_NODES * 128 * 2);
    float*    als  = (float*)alloc((size_t)N_NODES * 4 * 4);
    float*    ald  = (float*)alloc((size_t)N_NODES * 4 * 4);
    int*      deg  = (int*)alloc((size_t)N_NODES * 4);
    int*      curs = (int*)alloc((size_t)N_NODES * 4);
    int*      rowp = (int*)alloc((size_t)(N_NODES + 1) * 4);
    int*      col  = (int*)alloc((size_t)(N_EDGES + N_NODES) * 4);
    _Float16* wbuf = (_Float16*)alloc((size_t)(N_EDGES + N_NODES) * 4 * 2);
    int*      bsum = (int*)alloc(64 * 4);
    float*    sums = (float*)alloc(512 * 4);
    _Float16* WTh  = (_Float16*)alloc(128 * 128 * 2);
    float*    Wp   = (float*)alloc(128 * 128 * 4);
    float*    bp   = (float*)alloc(128 * 4);
    float*    g    = (float*)alloc(NGRAPHS * 128 * 4);
    float*    g2   = (float*)alloc(NGRAPHS * 128 * 4);
    float*    Wpc  = (float*)alloc(128 * 10 * 4);
    float*    bpc  = (float*)alloc(64);

    const int* esrc = ei;
    const int* edst = ei + N_EDGES;
    const int nb = divup(N_NODES, 1024);  // 49

    // ---- CSR build (deg starts at 1: self-loop per node) ----
    fill_i32<<<divup(N_NODES, 256), 256, 0, stream>>>(deg, 1, N_NODES);
    count_edges<<<divup(N_EDGES, 256), 256, 0, stream>>>(edst, deg, N_EDGES);
    scan_blocks<<<nb, 1024, 0, stream>>>(deg, rowp, bsum, N_NODES);
    scan_sums<<<1, 64, 0, stream>>>(bsum, nb);
    scan_add<<<divup(N_NODES, 256), 256, 0, stream>>>(rowp, curs, bsum, N_NODES, nb);
    scatter_edges_xcd<<<divup(N_EDGES, SCAT_CHUNK) * 8, 256, 0, stream>>>(esrc, edst, curs, col, N_EDGES);
    scatter_loops<<<divup(N_NODES, 256), 256, 0, stream>>>(curs, col, sums, N_NODES);

    // ---- h = relu(BN(x) @ w_feat) ----
    cast_stats<<<256, 256, 0, stream>>>(x, xh, N_NODES, sums);
    fold_t<<<128, 128, 0, stream>>>(sums, 1.f / N_NODES, bnf_g, bnf_b, w_feat, WTh, bp);
    gemm_mfma<<<divup(N_NODES, 64), 256, 0, stream>>>(xh, WTh, bp, h, N_NODES, 1,
                                                      nullptr, nullptr, nullptr, nullptr, sums);

    // ---- 3 GAT conv layers ----
    for (int i = 0; i < NCONV; ++i) {
        colstats_h<<<256, 256, 0, stream>>>(h, N_NODES, sums);
        fold_t<<<128, 128, 0, stream>>>(sums, 1.f / N_NODES, bnc_g + 128 * i, bnc_b + 128 * i,
                                        gat_w + 16384 * i, WTh, bp);
        gemm_mfma<<<divup(N_NODES, 64), 256, 0, stream>>>(h, WTh, bp, hp, N_NODES, 0,
                                                          gat_as + 128 * i, gat_ad + 128 * i,
                                                          als, ald, sums);
        gat_aggregate<<<divup(N_NODES, 4), 256, 0, stream>>>(hp, als, ald, rowp, col,
                                                             gat_b + 128 * i, h, wbuf, g, N_NODES);
    }

    // ---- pool + MLP head ----
    pool_kernel<<<divup(N_NODES, 32), 128, 0, stream>>>(h, batch, g, N_NODES, 32);
    colstats_small16<<<16, 256, 0, stream>>>(g, NGRAPHS, sums);
    fold_head<<<128, 128, 0, stream>>>(sums, 1.f / NGRAPHS, bnfc_g, bnfc_b, lin_w, lin_b, Wp, bp);
    gemm128<<<divup(NGRAPHS, 32), 256, 0, stream>>>(g, Wp, bp, g2, NGRAPHS, 1);
    colstats_small16<<<16, 256, 0, stream>>>(g2, NGRAPHS, sums + 256);
    fold_cls<<<1, 128, 0, stream>>>(sums + 256, 1.f / NGRAPHS, bnh_g, bnh_b, cls_w, cls_b, Wpc, bpc);
    final_kernel<<<NGRAPHS, 64, 0, stream>>>(g2, Wpc, bpc, out, NGRAPHS);
}

// Round 6
// 455.788 us; speedup vs baseline: 2.5100x; 1.0435x over previous
//
#include <hip/hip_runtime.h>
#include <math.h>

#define N_NODES 50000
#define N_EDGES 800000
#define NGRAPHS 256
#define NCONV 3
#define SCAT_CHUNK 2048

typedef _Float16 h4 __attribute__((ext_vector_type(4)));
typedef _Float16 h8 __attribute__((ext_vector_type(8)));
typedef float f32x4 __attribute__((ext_vector_type(4)));

static inline int divup(int a, int b) { return (a + b - 1) / b; }

__global__ void fill_i32(int* p, int v, int n) {
    int i = blockIdx.x * blockDim.x + threadIdx.x;
    if (i < n) p[i] = v;
}

// ---------------- CSR build ----------------
// XCD-sliced histogram: same trick as scatter — all atomics on a given deg line
// come from one blockIdx%8 class (likely one XCD): kills line ping-pong.
__global__ __launch_bounds__(256) void count_edges_xcd(const int* __restrict__ dst,
                                                       int* __restrict__ deg, int E) {
    int slice = blockIdx.x & 7;
    int base = (blockIdx.x >> 3) * SCAT_CHUNK;
    int lim = min(base + SCAT_CHUNK, E);
    int lo = slice * (N_NODES / 8);
    int hi = lo + (N_NODES / 8);
    for (int i = base + threadIdx.x; i < lim; i += 256) {
        int d = dst[i];
        if (d >= lo && d < hi) atomicAdd(&deg[d], 1);
    }
}

__global__ __launch_bounds__(1024) void scan_blocks(const int* __restrict__ deg,
                                                    int* __restrict__ excl,
                                                    int* __restrict__ bsum, int n) {
    __shared__ int buf[1024];
    int tid = threadIdx.x;
    int i = blockIdx.x * 1024 + tid;
    int v = (i < n) ? deg[i] : 0;
    buf[tid] = v;
    __syncthreads();
    for (int off = 1; off < 1024; off <<= 1) {
        int t = (tid >= off) ? buf[tid - off] : 0;
        __syncthreads();
        buf[tid] += t;
        __syncthreads();
    }
    if (i < n) excl[i] = buf[tid] - v;
    if (tid == 1023) bsum[blockIdx.x] = buf[1023];
}

__global__ void scan_sums(int* __restrict__ bsum, int nb) {
    int tid = threadIdx.x;  // 64
    int orig = (tid < nb) ? bsum[tid] : 0;
    int v = orig;
    for (int off = 1; off < 64; off <<= 1) {
        int t = __shfl_up(v, off, 64);
        if (tid >= off) v += t;
    }
    if (tid < nb) bsum[tid] = v - orig;
    if (tid == nb - 1) bsum[nb] = v;
}

__global__ void scan_add(int* __restrict__ row_ptr, int* __restrict__ cursor,
                         const int* __restrict__ bsum, int n, int nb) {
    int i = blockIdx.x * blockDim.x + threadIdx.x;
    if (i < n) {
        int v = row_ptr[i] + bsum[i >> 10];
        row_ptr[i] = v;
        cursor[i] = v;
    }
    if (i == 0) row_ptr[n] = bsum[nb];
}

// XCD-sliced scatter (see count_edges_xcd)
__global__ __launch_bounds__(256) void scatter_edges_xcd(const int* __restrict__ src,
                                                         const int* __restrict__ dst,
                                                         int* __restrict__ cursor,
                                                         int* __restrict__ col, int E) {
    int slice = blockIdx.x & 7;
    int base = (blockIdx.x >> 3) * SCAT_CHUNK;
    int lim = min(base + SCAT_CHUNK, E);
    int lo = slice * (N_NODES / 8);
    int hi = lo + (N_NODES / 8);
    for (int i = base + threadIdx.x; i < lim; i += 256) {
        int d = dst[i];
        if (d >= lo && d < hi) {
            int p = atomicAdd(&cursor[d], 1);
            col[p] = src[i];
        }
    }
}

// also zeroes sums[0..511] (runs before first stats)
__global__ void scatter_loops(int* __restrict__ cursor, int* __restrict__ col,
                              float* __restrict__ sums, int n) {
    if (blockIdx.x == 0 && threadIdx.x < 256) {
        sums[threadIdx.x] = 0.f;
        sums[256 + threadIdx.x] = 0.f;
    }
    int v = blockIdx.x * blockDim.x + threadIdx.x;
    if (v < n) {
        int p = atomicAdd(&cursor[v], 1);
        col[p] = v;
    }
}

// ---------------- fused cast f32->f16 + column stats ----------------
__global__ __launch_bounds__(256) void cast_stats(const float* __restrict__ x,
                                                  _Float16* __restrict__ y, int n,
                                                  float* __restrict__ sums) {
    __shared__ float S[16][128], S2[16][128];
    int tid = threadIdx.x;
    int c8 = (tid & 15) * 8;
    int rg = tid >> 4;
    float s[8] = {}, s2[8] = {};
    for (int r = blockIdx.x * 16 + rg; r < n; r += gridDim.x * 16) {
        const float4* p = (const float4*)&x[(size_t)r * 128 + c8];
        float4 v0 = p[0], v1 = p[1];
        float f[8] = {v0.x, v0.y, v0.z, v0.w, v1.x, v1.y, v1.z, v1.w};
        h8 o;
#pragma unroll
        for (int i = 0; i < 8; ++i) {
            o[i] = (_Float16)f[i];
            s[i] += f[i];
            s2[i] += f[i] * f[i];
        }
        *(h8*)&y[(size_t)r * 128 + c8] = o;
    }
#pragma unroll
    for (int i = 0; i < 8; ++i) { S[rg][c8 + i] = s[i]; S2[rg][c8 + i] = s2[i]; }
    __syncthreads();
    if (tid < 128) {
        float a = 0.f, b = 0.f;
#pragma unroll
        for (int k = 0; k < 16; ++k) { a += S[k][tid]; b += S2[k][tid]; }
        atomicAdd(&sums[tid], a);
        atomicAdd(&sums[128 + tid], b);
    }
}

// ---------------- column stats, fp16 input ----------------
__global__ __launch_bounds__(256) void colstats_h(const _Float16* __restrict__ x, int n,
                                                  float* __restrict__ sums) {
    __shared__ float S[16][128], S2[16][128];
    int tid = threadIdx.x;
    int c8 = (tid & 15) * 8;
    int rg = tid >> 4;
    float s[8] = {}, s2[8] = {};
    for (int r = blockIdx.x * 16 + rg; r < n; r += gridDim.x * 16) {
        h8 v = *(const h8*)&x[(size_t)r * 128 + c8];
#pragma unroll
        for (int i = 0; i < 8; ++i) {
            float f = (float)v[i];
            s[i] += f;
            s2[i] += f * f;
        }
    }
#pragma unroll
    for (int i = 0; i < 8; ++i) { S[rg][c8 + i] = s[i]; S2[rg][c8 + i] = s2[i]; }
    __syncthreads();
    if (tid < 128) {
        float a = 0.f, b = 0.f;
#pragma unroll
        for (int k = 0; k < 16; ++k) { a += S[k][tid]; b += S2[k][tid]; }
        atomicAdd(&sums[tid], a);
        atomicAdd(&sums[128 + tid], b);
    }
}

// ---------------- small (rows<=256) column stats ----------------
__global__ __launch_bounds__(256) void colstats_small16(const float* __restrict__ x, int rows,
                                                        float* __restrict__ sums) {
    __shared__ float S[16][128], S2[16][128];
    int tid = threadIdx.x;
    int c8 = (tid & 15) * 8;
    int rg = tid >> 4;
    float s[8] = {}, s2[8] = {};
    for (int r = blockIdx.x * 16 + rg; r < rows; r += gridDim.x * 16) {
        const float4* p = (const float4*)&x[(size_t)r * 128 + c8];
        float4 v0 = p[0], v1 = p[1];
        float f[8] = {v0.x, v0.y, v0.z, v0.w, v1.x, v1.y, v1.z, v1.w};
#pragma unroll
        for (int i = 0; i < 8; ++i) { s[i] += f[i]; s2[i] += f[i] * f[i]; }
    }
#pragma unroll
    for (int i = 0; i < 8; ++i) { S[rg][c8 + i] = s[i]; S2[rg][c8 + i] = s2[i]; }
    __syncthreads();
    if (tid < 128) {
        float a = 0.f, b = 0.f;
#pragma unroll
        for (int k = 0; k < 16; ++k) { a += S[k][tid]; b += S2[k][tid]; }
        atomicAdd(&sums[tid], a);
        atomicAdd(&sums[128 + tid], b);
    }
}

// ---------------- BN folds ----------------
__global__ __launch_bounds__(128) void fold_t(const float* __restrict__ sums, float inv_n,
                                              const float* __restrict__ gamma,
                                              const float* __restrict__ beta,
                                              const float* __restrict__ W,
                                              _Float16* __restrict__ WTh, float* __restrict__ bp) {
    int j = blockIdx.x, k = threadIdx.x;
    float mean = sums[k] * inv_n;
    float var = sums[128 + k] * inv_n - mean * mean;
    float sc = gamma[k] * rsqrtf(var + 1e-5f);
    float t = beta[k] - mean * sc;
    float w = W[k * 128 + j];
    WTh[j * 128 + k] = (_Float16)(sc * w);
    float pb = t * w;
    for (int off = 1; off < 64; off <<= 1) pb += __shfl_xor(pb, off, 64);
    __shared__ float r2[2];
    if ((k & 63) == 0) r2[k >> 6] = pb;
    __syncthreads();
    if (k == 0) bp[j] = r2[0] + r2[1];
}

__global__ __launch_bounds__(128) void fold_head(const float* __restrict__ sums, float inv_n,
                                                 const float* __restrict__ gamma,
                                                 const float* __restrict__ beta,
                                                 const float* __restrict__ W,
                                                 const float* __restrict__ extra,
                                                 float* __restrict__ Wp, float* __restrict__ bp) {
    int j = blockIdx.x, k = threadIdx.x;
    float mean = sums[k] * inv_n;
    float var = sums[128 + k] * inv_n - mean * mean;
    float sc = gamma[k] * rsqrtf(var + 1e-5f);
    float t = beta[k] - mean * sc;
    float w = W[k * 128 + j];
    Wp[k * 128 + j] = sc * w;
    float pb = t * w;
    for (int off = 1; off < 64; off <<= 1) pb += __shfl_xor(pb, off, 64);
    __shared__ float r2[2];
    if ((k & 63) == 0) r2[k >> 6] = pb;
    __syncthreads();
    if (k == 0) bp[j] = extra[j] + r2[0] + r2[1];
}

__global__ __launch_bounds__(128) void fold_cls(const float* __restrict__ sums, float inv_n,
                                                const float* __restrict__ gamma,
                                                const float* __restrict__ beta,
                                                const float* __restrict__ W,
                                                const float* __restrict__ b,
                                                float* __restrict__ Wp, float* __restrict__ bp) {
    __shared__ float sS[128], part[128][10];
    int k = threadIdx.x;
    float mean = sums[k] * inv_n;
    float var = sums[128 + k] * inv_n - mean * mean;
    float sc = gamma[k] * rsqrtf(var + 1e-5f);
    float t = beta[k] - mean * sc;
    sS[k] = sc;
#pragma unroll
    for (int j = 0; j < 10; ++j) part[k][j] = t * W[k * 10 + j];
    __syncthreads();
    for (int i = k; i < 1280; i += 128) Wp[i] = sS[i / 10] * W[i];
    if (k < 10) {
        float acc = b[k];
        for (int kk = 0; kk < 128; ++kk) acc += part[kk][k];
        bp[k] = acc;
    }
}

// ---------------- MFMA fp16 GEMM ----------------
__global__ __launch_bounds__(256) void gemm_mfma(const _Float16* __restrict__ Ah,
                                                 const _Float16* __restrict__ WTh,
                                                 const float* __restrict__ bp,
                                                 _Float16* __restrict__ outh, int n, int relu,
                                                 const float* __restrict__ asrc,
                                                 const float* __restrict__ adst,
                                                 float* __restrict__ als,
                                                 float* __restrict__ ald,
                                                 float* __restrict__ sums_zero) {
    __shared__ _Float16 Wl[128 * 136];
    int tid = threadIdx.x;
    if (blockIdx.x == 0 && tid < 256 && sums_zero) sums_zero[tid] = 0.f;
    for (int i = tid; i < 2048; i += 256) {
        int r = i >> 4, s = i & 15;
        *(h8*)&Wl[r * 136 + s * 8] = *(const h8*)&WTh[r * 128 + s * 8];
    }
    __syncthreads();
    int lane = tid & 63, wid = tid >> 6;
    int m = lane & 15, quad = lane >> 4;
    int rbase = blockIdx.x * 64 + wid * 16;
    if (rbase >= n) return;

    const _Float16* arow = Ah + (size_t)(rbase + m) * 128 + quad * 8;
    h8 af0 = *(const h8*)(arow);
    h8 af1 = *(const h8*)(arow + 32);
    h8 af2 = *(const h8*)(arow + 64);
    h8 af3 = *(const h8*)(arow + 96);

    float ps[4][4] = {}, pd[4][4] = {};
    const bool do_al = (asrc != nullptr);

#pragma unroll
    for (int t = 0; t < 8; ++t) {
        const _Float16* wrow = &Wl[(t * 16 + m) * 136 + quad * 8];
        f32x4 acc = {0.f, 0.f, 0.f, 0.f};
        acc = __builtin_amdgcn_mfma_f32_16x16x32_f16(af0, *(const h8*)(wrow), acc, 0, 0, 0);
        acc = __builtin_amdgcn_mfma_f32_16x16x32_f16(af1, *(const h8*)(wrow + 32), acc, 0, 0, 0);
        acc = __builtin_amdgcn_mfma_f32_16x16x32_f16(af2, *(const h8*)(wrow + 64), acc, 0, 0, 0);
        acc = __builtin_amdgcn_mfma_f32_16x16x32_f16(af3, *(const h8*)(wrow + 96), acc, 0, 0, 0);
        int j = t * 16 + m;
        float bj = bp[j];
        float avs = 0.f, avd = 0.f;
        if (do_al) { avs = asrc[j]; avd = adst[j]; }
        int hh = t >> 1;
#pragma unroll
        for (int r = 0; r < 4; ++r) {
            float o = acc[r] + bj;
            if (do_al) {
                ps[r][hh] += o * avs;
                pd[r][hh] += o * avd;
            }
            float v = relu ? fmaxf(o, 0.f) : o;
            int row = rbase + quad * 4 + r;
            outh[(size_t)row * 128 + j] = (_Float16)v;
        }
    }
    if (do_al) {
#pragma unroll
        for (int r = 0; r < 4; ++r) {
#pragma unroll
            for (int hh = 0; hh < 4; ++hh) {
                float v = ps[r][hh];
                v += __shfl_xor(v, 1, 64); v += __shfl_xor(v, 2, 64);
                v += __shfl_xor(v, 4, 64); v += __shfl_xor(v, 8, 64);
                float w = pd[r][hh];
                w += __shfl_xor(w, 1, 64); w += __shfl_xor(w, 2, 64);
                w += __shfl_xor(w, 4, 64); w += __shfl_xor(w, 8, 64);
                if (m == 0) {
                    int row = rbase + quad * 4 + r;
                    als[row * 4 + hh] = v;
                    ald[row * 4 + hh] = w;
                }
            }
        }
    }
}

__device__ __forceinline__ float leaky(float x) { return fmaxf(x, 0.2f * x); }

// ---------------- GAT aggregation: single fused pass ----------------
// One wave per dst node; 4 edge-quads x 16 feature-lanes. Each lane accumulates
// Sum(w*h[f0..f0+7]) and Sum(w) for its head (w = exp(shifted clamped logit),
// softmax shift-invariant => out = Sum(w*h)/Sum(w) exactly).
__global__ __launch_bounds__(256) void gat_aggregate(const _Float16* __restrict__ hp,
                                                     const float* __restrict__ al_s,
                                                     const float* __restrict__ al_d,
                                                     const int* __restrict__ row_ptr,
                                                     const int* __restrict__ col,
                                                     const float* __restrict__ bias,
                                                     _Float16* __restrict__ h_out,
                                                     float* __restrict__ g_zero, int n) {
    if (blockIdx.x < 128) g_zero[blockIdx.x * 256 + threadIdx.x] = 0.f;
    int lane = threadIdx.x & 63;
    int node = blockIdx.x * 4 + (threadIdx.x >> 6);
    if (node >= n) return;
    int beg = row_ptr[node], end = row_ptr[node + 1];
    int q = lane >> 4, l4 = lane & 15;
    int head = l4 >> 2;
    int f0 = l4 * 8;
    float adh = al_d[node * 4 + head];
    float ch = leaky(adh);
    const _Float16* hpf = hp + f0;
    float ws = 0.f;
    float a0 = 0.f, a1 = 0.f, a2 = 0.f, a3 = 0.f, a4 = 0.f, a5 = 0.f, a6 = 0.f, a7 = 0.f;
    for (int e = beg + q; e < end; e += 4) {
        unsigned s = (unsigned)col[e];
        float as = al_s[s * 4 + head];
        float w = __expf(fminf(leaky(as + adh) - ch, 10.f));
        h8 hv = *(const h8*)(hpf + (size_t)s * 128);
        ws += w;
        a0 += (float)hv[0] * w; a1 += (float)hv[1] * w;
        a2 += (float)hv[2] * w; a3 += (float)hv[3] * w;
        a4 += (float)hv[4] * w; a5 += (float)hv[5] * w;
        a6 += (float)hv[6] * w; a7 += (float)hv[7] * w;
    }
#pragma unroll
    for (int off = 16; off <= 32; off <<= 1) {
        ws += __shfl_xor(ws, off, 64);
        a0 += __shfl_xor(a0, off, 64); a1 += __shfl_xor(a1, off, 64);
        a2 += __shfl_xor(a2, off, 64); a3 += __shfl_xor(a3, off, 64);
        a4 += __shfl_xor(a4, off, 64); a5 += __shfl_xor(a5, off, 64);
        a6 += __shfl_xor(a6, off, 64); a7 += __shfl_xor(a7, off, 64);
    }
    if (q == 0) {
        float inv = 1.f / (ws + 1e-16f);
        float4 b0 = *(const float4*)&bias[f0];
        float4 b1 = *(const float4*)&bias[f0 + 4];
        h8 ov;
        ov[0] = (_Float16)fmaxf(a0 * inv + b0.x, 0.f);
        ov[1] = (_Float16)fmaxf(a1 * inv + b0.y, 0.f);
        ov[2] = (_Float16)fmaxf(a2 * inv + b0.z, 0.f);
        ov[3] = (_Float16)fmaxf(a3 * inv + b0.w, 0.f);
        ov[4] = (_Float16)fmaxf(a4 * inv + b1.x, 0.f);
        ov[5] = (_Float16)fmaxf(a5 * inv + b1.y, 0.f);
        ov[6] = (_Float16)fmaxf(a6 * inv + b1.z, 0.f);
        ov[7] = (_Float16)fmaxf(a7 * inv + b1.w, 0.f);
        *(h8*)&h_out[(size_t)node * 128 + f0] = ov;
    }
}

// ---------------- pooling (batch sorted), chunk=32 ----------------
__global__ void pool_kernel(const _Float16* __restrict__ h, const int* __restrict__ batch,
                            float* __restrict__ g, int n, int chunk) {
    int f = threadIdx.x;  // 128
    int a = blockIdx.x * chunk;
    if (a >= n) return;
    int b = min(n, a + chunk);
    float acc = 0.f;
    int cur = batch[a];
    for (int i = a; i < b; ++i) {
        int bi = batch[i];
        if (bi != cur) {
            atomicAdd(&g[cur * 128 + f], acc);
            acc = 0.f;
            cur = bi;
        }
        acc += (float)h[(size_t)i * 128 + f];
    }
    atomicAdd(&g[cur * 128 + f], acc);
}

// ---------------- head GEMM (f32, n=256) ----------------
__global__ __launch_bounds__(256) void gemm128(const float* __restrict__ A,
                                               const float* __restrict__ Wp,
                                               const float* __restrict__ bp,
                                               float* __restrict__ out, int n, int relu) {
    __shared__ float Wl[128 * 128];
    __shared__ float hT[128 * 32];
    int tid = threadIdx.x;
    for (int i = tid; i < 4096; i += 256) {
        ((float4*)Wl)[i] = ((const float4*)Wp)[i];
    }
    int base = blockIdx.x * 32;
    for (int pass = 0; pass < 4; ++pass) {
        int r = (tid >> 5) + pass * 8;
        int c4 = tid & 31;
        int row = base + r;
        float4 v = (row < n) ? ((const float4*)(A + (size_t)row * 128))[c4]
                             : make_float4(0.f, 0.f, 0.f, 0.f);
        hT[(c4 * 4 + 0) * 32 + r] = v.x;
        hT[(c4 * 4 + 1) * 32 + r] = v.y;
        hT[(c4 * 4 + 2) * 32 + r] = v.z;
        hT[(c4 * 4 + 3) * 32 + r] = v.w;
    }
    __syncthreads();
    int tx = tid & 31, ty = tid >> 5;
    int j0 = tx * 4, r0 = ty * 4;
    float acc[4][4] = {};
#pragma unroll 8
    for (int k = 0; k < 128; ++k) {
        float4 a = *(const float4*)&hT[k * 32 + r0];
        float4 w = *(const float4*)&Wl[k * 128 + j0];
        acc[0][0] += a.x * w.x; acc[0][1] += a.x * w.y; acc[0][2] += a.x * w.z; acc[0][3] += a.x * w.w;
        acc[1][0] += a.y * w.x; acc[1][1] += a.y * w.y; acc[1][2] += a.y * w.z; acc[1][3] += a.y * w.w;
        acc[2][0] += a.z * w.x; acc[2][1] += a.z * w.y; acc[2][2] += a.z * w.z; acc[2][3] += a.z * w.w;
        acc[3][0] += a.w * w.x; acc[3][1] += a.w * w.y; acc[3][2] += a.w * w.z; acc[3][3] += a.w * w.w;
    }
    float4 bb = *(const float4*)&bp[j0];
    for (int i2 = 0; i2 < 4; ++i2) {
        int row = base + r0 + i2;
        if (row < n) {
            float4 o = make_float4(acc[i2][0] + bb.x, acc[i2][1] + bb.y,
                                   acc[i2][2] + bb.z, acc[i2][3] + bb.w);
            if (relu) {
                o.x = fmaxf(o.x, 0.f); o.y = fmaxf(o.y, 0.f);
                o.z = fmaxf(o.z, 0.f); o.w = fmaxf(o.w, 0.f);
            }
            *(float4*)&out[(size_t)row * 128 + j0] = o;
        }
    }
}

// ---------------- final classifier + log_softmax ----------------
__global__ __launch_bounds__(64) void final_kernel(const float* __restrict__ g2,
                                                   const float* __restrict__ Wpc,
                                                   const float* __restrict__ bpc,
                                                   float* __restrict__ out, int rows) {
    int r = blockIdx.x;
    if (r >= rows) return;
    int lane = threadIdx.x;
    float logit[10] = {};
    for (int k = lane; k < 128; k += 64) {
        float gv = g2[r * 128 + k];
#pragma unroll
        for (int j = 0; j < 10; ++j) logit[j] += gv * Wpc[k * 10 + j];
    }
#pragma unroll
    for (int j = 0; j < 10; ++j)
        for (int off = 1; off < 64; off <<= 1) logit[j] += __shfl_xor(logit[j], off, 64);
    if (lane == 0) {
        float m = -1e30f;
#pragma unroll
        for (int j = 0; j < 10; ++j) { logit[j] += bpc[j]; m = fmaxf(m, logit[j]); }
        float sum = 0.f;
#pragma unroll
        for (int j = 0; j < 10; ++j) sum += expf(logit[j] - m);
        float lse = m + logf(sum);
#pragma unroll
        for (int j = 0; j < 10; ++j) out[r * 10 + j] = logit[j] - lse;
    }
}

extern "C" void kernel_launch(void* const* d_in, const int* in_sizes, int n_in,
                              void* d_out, int out_size, void* d_ws, size_t ws_size,
                              hipStream_t stream) {
    const float* x      = (const float*)d_in[0];
    const int*   ei     = (const int*)d_in[1];
    const int*   batch  = (const int*)d_in[2];
    const float* w_feat = (const float*)d_in[3];
    const float* bnf_g  = (const float*)d_in[4];
    const float* bnf_b  = (const float*)d_in[5];
    const float* bnc_g  = (const float*)d_in[6];
    const float* bnc_b  = (const float*)d_in[7];
    const float* gat_w  = (const float*)d_in[8];
    const float* gat_as = (const float*)d_in[9];
    const float* gat_ad = (const float*)d_in[10];
    const float* gat_b  = (const float*)d_in[11];
    const float* bnfc_g = (const float*)d_in[12];
    const float* bnfc_b = (const float*)d_in[13];
    const float* lin_w  = (const float*)d_in[14];
    const float* lin_b  = (const float*)d_in[15];
    const float* bnh_g  = (const float*)d_in[16];
    const float* bnh_b  = (const float*)d_in[17];
    const float* cls_w  = (const float*)d_in[18];
    const float* cls_b  = (const float*)d_in[19];
    float* out = (float*)d_out;

    char* ws = (char*)d_ws;
    size_t off = 0;
    auto alloc = [&](size_t bytes) -> void* {
        void* p = ws + off;
        off = (off + bytes + 255) & ~(size_t)255;
        return p;
    };
    _Float16* xh   = (_Float16*)alloc((size_t)N_NODES * 128 * 2);
    _Float16* h    = (_Float16*)alloc((size_t)N_NODES * 128 * 2);
    _Float16* hp   = (_Float16*)alloc((size_t)N_NODES * 128 * 2);
    float*    als  = (float*)alloc((size_t)N_NODES * 4 * 4);
    float*    ald  = (float*)alloc((size_t)N_NODES * 4 * 4);
    int*      deg  = (int*)alloc((size_t)N_NODES * 4);
    int*      curs = (int*)alloc((size_t)N_NODES * 4);
    int*      rowp = (int*)alloc((size_t)(N_NODES + 1) * 4);
    int*      col  = (int*)alloc((size_t)(N_EDGES + N_NODES) * 4);
    int*      bsum = (int*)alloc(64 * 4);
    float*    sums = (float*)alloc(512 * 4);
    _Float16* WTh  = (_Float16*)alloc(128 * 128 * 2);
    float*    Wp   = (float*)alloc(128 * 128 * 4);
    float*    bp   = (float*)alloc(128 * 4);
    float*    g    = (float*)alloc(NGRAPHS * 128 * 4);
    float*    g2   = (float*)alloc(NGRAPHS * 128 * 4);
    float*    Wpc  = (float*)alloc(128 * 10 * 4);
    float*    bpc  = (float*)alloc(64);

    const int* esrc = ei;
    const int* edst = ei + N_EDGES;
    const int nb = divup(N_NODES, 1024);  // 49

    // ---- CSR build (deg starts at 1: self-loop per node) ----
    fill_i32<<<divup(N_NODES, 256), 256, 0, stream>>>(deg, 1, N_NODES);
    count_edges_xcd<<<divup(N_EDGES, SCAT_CHUNK) * 8, 256, 0, stream>>>(edst, deg, N_EDGES);
    scan_blocks<<<nb, 1024, 0, stream>>>(deg, rowp, bsum, N_NODES);
    scan_sums<<<1, 64, 0, stream>>>(bsum, nb);
    scan_add<<<divup(N_NODES, 256), 256, 0, stream>>>(rowp, curs, bsum, N_NODES, nb);
    scatter_edges_xcd<<<divup(N_EDGES, SCAT_CHUNK) * 8, 256, 0, stream>>>(esrc, edst, curs, col, N_EDGES);
    scatter_loops<<<divup(N_NODES, 256), 256, 0, stream>>>(curs, col, sums, N_NODES);

    // ---- h = relu(BN(x) @ w_feat) ----
    cast_stats<<<256, 256, 0, stream>>>(x, xh, N_NODES, sums);
    fold_t<<<128, 128, 0, stream>>>(sums, 1.f / N_NODES, bnf_g, bnf_b, w_feat, WTh, bp);
    gemm_mfma<<<divup(N_NODES, 64), 256, 0, stream>>>(xh, WTh, bp, h, N_NODES, 1,
                                                      nullptr, nullptr, nullptr, nullptr, sums);

    // ---- 3 GAT conv layers ----
    for (int i = 0; i < NCONV; ++i) {
        colstats_h<<<256, 256, 0, stream>>>(h, N_NODES, sums);
        fold_t<<<128, 128, 0, stream>>>(sums, 1.f / N_NODES, bnc_g + 128 * i, bnc_b + 128 * i,
                                        gat_w + 16384 * i, WTh, bp);
        gemm_mfma<<<divup(N_NODES, 64), 256, 0, stream>>>(h, WTh, bp, hp, N_NODES, 0,
                                                          gat_as + 128 * i, gat_ad + 128 * i,
                                                          als, ald, sums);
        gat_aggregate<<<divup(N_NODES, 4), 256, 0, stream>>>(hp, als, ald, rowp, col,
                                                             gat_b + 128 * i, h, g, N_NODES);
    }

    // ---- pool + MLP head ----
    pool_kernel<<<divup(N_NODES, 32), 128, 0, stream>>>(h, batch, g, N_NODES, 32);
    colstats_small16<<<16, 256, 0, stream>>>(g, NGRAPHS, sums);
    fold_head<<<128, 128, 0, stream>>>(sums, 1.f / NGRAPHS, bnfc_g, bnfc_b, lin_w, lin_b, Wp, bp);
    gemm128<<<divup(NGRAPHS, 32), 256, 0, stream>>>(g, Wp, bp, g2, NGRAPHS, 1);
    colstats_small16<<<16, 256, 0, stream>>>(g2, NGRAPHS, sums + 256);
    fold_cls<<<1, 128, 0, stream>>>(sums + 256, 1.f / NGRAPHS, bnh_g, bnh_b, cls_w, cls_b, Wpc, bpc);
    final_kernel<<<NGRAPHS, 64, 0, stream>>>(g2, Wpc, bpc, out, NGRAPHS);
}